// Round 1
// baseline (1086.338 us; speedup 1.0000x reference)
//
#include <hip/hip_runtime.h>
#include <cmath>

#define NN 20000
#define NE 200000
#define EPB 64   // edges per block in edge kernel (2 rounds of 32)

__device__ __forceinline__ float4 ld4(const float* p){ return *(const float4*)p; }

// O[m][j] = sum_k A[m][k]*B[k][j] + bias[j]; one thread per 4 consecutive j
__global__ void gemm4(const float* __restrict__ A, const float* __restrict__ B,
                      const float* __restrict__ bias, float* __restrict__ O,
                      int M, int K, int Nout) {
  int jt = Nout >> 2;
  int idx = blockIdx.x * 256 + threadIdx.x;
  if (idx >= M * jt) return;
  int m = idx / jt;
  int j4 = (idx - m * jt) << 2;
  const float* a = A + (long)m * K;
  const float* b = B + j4;
  float ax = 0.f, ay = 0.f, az = 0.f, aw = 0.f;
  for (int k = 0; k < K; k++) {
    float av = a[k];
    float4 bv = ld4(b + (long)k * Nout);
    ax = fmaf(av, bv.x, ax); ay = fmaf(av, bv.y, ay);
    az = fmaf(av, bv.z, az); aw = fmaf(av, bv.w, aw);
  }
  if (bias) { float4 bb = ld4(bias + j4); ax += bb.x; ay += bb.y; az += bb.z; aw += bb.w; }
  *(float4*)(O + (long)m * Nout + j4) = make_float4(ax, ay, az, aw);
}

__global__ void zero_i32(int* __restrict__ p, int n) {
  int i = blockIdx.x * 256 + threadIdx.x;
  if (i < n) p[i] = 0;
}

__global__ void count_deg(const int* __restrict__ dst, int* __restrict__ deg) {
  int e = blockIdx.x * 256 + threadIdx.x;
  if (e < NE) atomicAdd(&deg[dst[e]], 1);
}

// single-block exclusive scan over NN degrees -> off[0..NN]
__global__ void scan_offsets(const int* __restrict__ deg, int* __restrict__ off) {
  __shared__ int buf[1024];
  __shared__ int carry;
  int t = threadIdx.x;
  if (t == 0) carry = 0;
  __syncthreads();
  for (int base = 0; base < NN; base += 1024) {
    int v = (base + t < NN) ? deg[base + t] : 0;
    buf[t] = v;
    __syncthreads();
    for (int s = 1; s < 1024; s <<= 1) {
      int x = (t >= s) ? buf[t - s] : 0;
      __syncthreads();
      buf[t] += x;
      __syncthreads();
    }
    if (base + t < NN) off[base + t] = carry + buf[t] - v;
    __syncthreads();
    if (t == 0) carry += buf[1023];
    __syncthreads();
  }
  if (t == 0) off[NN] = carry;
}

__global__ void fill_csr(const int* __restrict__ dst, const int* __restrict__ off,
                         int* __restrict__ cursor, int* __restrict__ elist) {
  int e = blockIdx.x * 256 + threadIdx.x;
  if (e >= NE) return;
  int d = dst[e];
  int p = atomicAdd(&cursor[d], 1);
  elist[off[d] + p] = e;
}

// Fused edge pass: f_out = hni[src]+hnj[dst]+f@Wfij+bias ; scores ; f-update
// One wave handles 8 edges; lane c owns channels 4c..4c+3 of the 256 (head = c>>4).
__global__ __launch_bounds__(256) void edge_kernel(
    const float* __restrict__ f_cur, const float* __restrict__ hni,
    const float* __restrict__ hnj, const float* __restrict__ Wf_l,
    const float* __restrict__ be_l, const float* __restrict__ attn_l,
    const int* __restrict__ src, const int* __restrict__ dst,
    float* __restrict__ score, float* __restrict__ f_next)
{
  __shared__ float Wsh[64 * 256];   // exactly 64 KB
  int t = threadIdx.x;
  #pragma unroll
  for (int i = 0; i < 16; i++) {
    int o = t * 4 + i * 1024;
    *(float4*)&Wsh[o] = ld4(Wf_l + o);
  }
  __syncthreads();
  int lane = t & 63, wv = t >> 6;
  float4 bias4 = ld4(be_l + 4 * lane);
  float4 attn4 = ld4(attn_l + 4 * lane);
  int base = blockIdx.x * EPB + wv * 8;
  for (int r = 0; r < EPB / 32; r++) {
    int ew = base + r * 32;
    float4 acc[8];
    #pragma unroll
    for (int i = 0; i < 8; i++) {
      int e = ew + i;
      int s = src[e]; int d = dst[e];
      float4 a = ld4(hni + (long)s * 256 + 4 * lane);
      float4 b = ld4(hnj + (long)d * 256 + 4 * lane);
      acc[i].x = a.x + b.x + bias4.x;
      acc[i].y = a.y + b.y + bias4.y;
      acc[i].z = a.z + b.z + bias4.z;
      acc[i].w = a.w + b.w + bias4.w;
    }
    const float* frow = f_cur + (long)ew * 64;
    #pragma unroll 2
    for (int k = 0; k < 64; k += 4) {
      float4 w0 = *(const float4*)&Wsh[(k + 0) * 256 + 4 * lane];
      float4 w1 = *(const float4*)&Wsh[(k + 1) * 256 + 4 * lane];
      float4 w2 = *(const float4*)&Wsh[(k + 2) * 256 + 4 * lane];
      float4 w3 = *(const float4*)&Wsh[(k + 3) * 256 + 4 * lane];
      #pragma unroll
      for (int i = 0; i < 8; i++) {
        float4 fv = ld4(frow + i * 64 + k);   // wave-uniform, L1-hot
        acc[i].x = fmaf(fv.x, w0.x, acc[i].x); acc[i].y = fmaf(fv.x, w0.y, acc[i].y);
        acc[i].z = fmaf(fv.x, w0.z, acc[i].z); acc[i].w = fmaf(fv.x, w0.w, acc[i].w);
        acc[i].x = fmaf(fv.y, w1.x, acc[i].x); acc[i].y = fmaf(fv.y, w1.y, acc[i].y);
        acc[i].z = fmaf(fv.y, w1.z, acc[i].z); acc[i].w = fmaf(fv.y, w1.w, acc[i].w);
        acc[i].x = fmaf(fv.z, w2.x, acc[i].x); acc[i].y = fmaf(fv.z, w2.y, acc[i].y);
        acc[i].z = fmaf(fv.z, w2.z, acc[i].z); acc[i].w = fmaf(fv.z, w2.w, acc[i].w);
        acc[i].x = fmaf(fv.w, w3.x, acc[i].x); acc[i].y = fmaf(fv.w, w3.y, acc[i].y);
        acc[i].z = fmaf(fv.w, w3.z, acc[i].z); acc[i].w = fmaf(fv.w, w3.w, acc[i].w);
      }
    }
    #pragma unroll
    for (int i = 0; i < 8; i++) {
      int e = ew + i;
      float4 fo = acc[i];
      // leaky-relu + attention score (reduce within 16-lane head group)
      float lx = fo.x > 0.f ? fo.x : 0.01f * fo.x;
      float ly = fo.y > 0.f ? fo.y : 0.01f * fo.y;
      float lz = fo.z > 0.f ? fo.z : 0.01f * fo.z;
      float lw = fo.w > 0.f ? fo.w : 0.01f * fo.w;
      float part = lx * attn4.x + ly * attn4.y + lz * attn4.z + lw * attn4.w;
      part += __shfl_xor(part, 1);
      part += __shfl_xor(part, 2);
      part += __shfl_xor(part, 4);
      part += __shfl_xor(part, 8);
      if ((lane & 15) == 0) score[e * 4 + (lane >> 4)] = part;
      // f update: head-mean -> InstanceNorm -> ELU  (uses pre-activation fo)
      float vx = fo.x, vy = fo.y, vz = fo.z, vw = fo.w;
      vx += __shfl_xor(vx, 16); vy += __shfl_xor(vy, 16); vz += __shfl_xor(vz, 16); vw += __shfl_xor(vw, 16);
      vx += __shfl_xor(vx, 32); vy += __shfl_xor(vy, 32); vz += __shfl_xor(vz, 32); vw += __shfl_xor(vw, 32);
      vx *= 0.25f; vy *= 0.25f; vz *= 0.25f; vw *= 0.25f;
      float s1 = vx + vy + vz + vw;
      float s2 = vx * vx + vy * vy + vz * vz + vw * vw;
      s1 += __shfl_xor(s1, 1); s2 += __shfl_xor(s2, 1);
      s1 += __shfl_xor(s1, 2); s2 += __shfl_xor(s2, 2);
      s1 += __shfl_xor(s1, 4); s2 += __shfl_xor(s2, 4);
      s1 += __shfl_xor(s1, 8); s2 += __shfl_xor(s2, 8);
      float mean = s1 * 0.015625f;
      float var  = s2 * 0.015625f - mean * mean;
      float rs = rsqrtf(var + 1e-5f);
      if (lane < 16) {
        float ox = (vx - mean) * rs; ox = ox > 0.f ? ox : expm1f(ox);
        float oy = (vy - mean) * rs; oy = oy > 0.f ? oy : expm1f(oy);
        float oz = (vz - mean) * rs; oz = oz > 0.f ? oz : expm1f(oz);
        float ow = (vw - mean) * rs; ow = ow > 0.f ? ow : expm1f(ow);
        *(float4*)(f_next + (long)e * 64 + 4 * lane) = make_float4(ox, oy, oz, ow);
      }
    }
  }
}

// One wave per dst node: softmax over incoming edges + weighted hproj[src] sum
// + head-mean + InstanceNorm + ELU.
__global__ __launch_bounds__(256) void agg_kernel(
    const float* __restrict__ hproj, const float* __restrict__ score,
    const int* __restrict__ src, const int* __restrict__ elist,
    const int* __restrict__ off, float* __restrict__ h_next)
{
  int gw = (blockIdx.x * 256 + threadIdx.x) >> 6;
  int lane = threadIdx.x & 63;
  if (gw >= NN) return;
  int o0 = off[gw], o1 = off[gw + 1];
  int hh = lane >> 4;
  if (o0 == o1) {
    if (lane < 16) *(float4*)(h_next + (long)gw * 64 + 4 * lane) = make_float4(0.f, 0.f, 0.f, 0.f);
    return;
  }
  float mx = -3.0e38f;
  for (int i = o0; i < o1; i++) {
    int e = elist[i];
    mx = fmaxf(mx, score[e * 4 + hh]);
  }
  float ax = 0.f, ay = 0.f, az = 0.f, aw = 0.f, den = 0.f;
  for (int i = o0; i < o1; i++) {
    int e = elist[i];
    float w = __expf(score[e * 4 + hh] - mx);
    den += w;
    float4 hp = ld4(hproj + (long)src[e] * 256 + 4 * lane);
    ax = fmaf(w, hp.x, ax); ay = fmaf(w, hp.y, ay);
    az = fmaf(w, hp.z, az); aw = fmaf(w, hp.w, aw);
  }
  float inv = 1.f / den;
  float vx = ax * inv, vy = ay * inv, vz = az * inv, vw = aw * inv;
  vx += __shfl_xor(vx, 16); vy += __shfl_xor(vy, 16); vz += __shfl_xor(vz, 16); vw += __shfl_xor(vw, 16);
  vx += __shfl_xor(vx, 32); vy += __shfl_xor(vy, 32); vz += __shfl_xor(vz, 32); vw += __shfl_xor(vw, 32);
  vx *= 0.25f; vy *= 0.25f; vz *= 0.25f; vw *= 0.25f;
  float s1 = vx + vy + vz + vw;
  float s2 = vx * vx + vy * vy + vz * vz + vw * vw;
  s1 += __shfl_xor(s1, 1); s2 += __shfl_xor(s2, 1);
  s1 += __shfl_xor(s1, 2); s2 += __shfl_xor(s2, 2);
  s1 += __shfl_xor(s1, 4); s2 += __shfl_xor(s2, 4);
  s1 += __shfl_xor(s1, 8); s2 += __shfl_xor(s2, 8);
  float mean = s1 * 0.015625f;
  float var  = s2 * 0.015625f - mean * mean;
  float rs = rsqrtf(var + 1e-5f);
  if (lane < 16) {
    float ox = (vx - mean) * rs; ox = ox > 0.f ? ox : expm1f(ox);
    float oy = (vy - mean) * rs; oy = oy > 0.f ? oy : expm1f(oy);
    float oz = (vz - mean) * rs; oz = oz > 0.f ? oz : expm1f(oz);
    float ow = (vw - mean) * rs; ow = ow > 0.f ? ow : expm1f(ow);
    *(float4*)(h_next + (long)gw * 64 + 4 * lane) = make_float4(ox, oy, oz, ow);
  }
}

extern "C" void kernel_launch(void* const* d_in, const int* in_sizes, int n_in,
                              void* d_out, int out_size, void* d_ws, size_t ws_size,
                              hipStream_t stream) {
  const float* x      = (const float*)d_in[0];
  const float* efeat  = (const float*)d_in[1];
  const int*   src    = (const int*)d_in[2];
  const int*   dst    = (const int*)d_in[3];
  const float* Wn0    = (const float*)d_in[4];
  const float* bn0    = (const float*)d_in[5];
  const float* We0    = (const float*)d_in[6];
  const float* be0    = (const float*)d_in[7];
  const float* Wnode  = (const float*)d_in[8];
  const float* bnode  = (const float*)d_in[9];
  const float* Wni    = (const float*)d_in[10];
  const float* Wnj    = (const float*)d_in[11];
  const float* Wfij   = (const float*)d_in[12];
  const float* attn   = (const float*)d_in[13];
  const float* bias_e = (const float*)d_in[14];
  const float* Wf     = (const float*)d_in[15];
  const float* bf     = (const float*)d_in[16];
  float* out = (float*)d_out;

  char* w = (char*)d_ws;
  auto alloc = [&](size_t nbytes) { char* p = w; w += (nbytes + 255) & ~(size_t)255; return p; };
  float* h_a  = (float*)alloc((size_t)NN * 64 * 4);
  float* h_b  = (float*)alloc((size_t)NN * 64 * 4);
  float* f_a  = (float*)alloc((size_t)NE * 64 * 4);
  float* f_b  = (float*)alloc((size_t)NE * 64 * 4);
  float* hni  = (float*)alloc((size_t)NN * 256 * 4);
  float* hnj  = (float*)alloc((size_t)NN * 256 * 4);
  float* hpj  = (float*)alloc((size_t)NN * 256 * 4);
  float* sc   = (float*)alloc((size_t)NE * 4 * 4);
  int* deg    = (int*)alloc((size_t)NN * 4);
  int* cursor = (int*)alloc((size_t)NN * 4);
  int* off    = (int*)alloc((size_t)(NN + 1) * 4);
  int* elist  = (int*)alloc((size_t)NE * 4);

  // input projections
  gemm4<<<(NN * 16 + 255) / 256, 256, 0, stream>>>(x, Wn0, bn0, h_a, NN, 65, 64);
  gemm4<<<(NE * 16 + 255) / 256, 256, 0, stream>>>(efeat, We0, be0, f_a, NE, 15, 64);

  // CSR over dst
  zero_i32<<<(NN + 255) / 256, 256, 0, stream>>>(deg, NN);
  zero_i32<<<(NN + 255) / 256, 256, 0, stream>>>(cursor, NN);
  count_deg<<<(NE + 255) / 256, 256, 0, stream>>>(dst, deg);
  scan_offsets<<<1, 1024, 0, stream>>>(deg, off);
  fill_csr<<<(NE + 255) / 256, 256, 0, stream>>>(dst, off, cursor, elist);

  float* hc = h_a; float* hn = h_b;
  float* fc = f_a; float* fn = f_b;
  for (int l = 0; l < 2; l++) {
    const float* Wni_l  = Wni  + (size_t)l * 64 * 256;
    const float* Wnj_l  = Wnj  + (size_t)l * 64 * 256;
    const float* Wnd_l  = Wnode + (size_t)l * 64 * 256;
    const float* Wfij_l = Wfij + (size_t)l * 64 * 256;
    const float* bnd_l  = bnode + (size_t)l * 256;
    const float* be_l   = bias_e + (size_t)l * 256;
    const float* at_l   = attn + (size_t)l * 256;
    int tn = NN * 64;  // M*(Nout/4) threads for Nout=256
    gemm4<<<(tn + 255) / 256, 256, 0, stream>>>(hc, Wni_l, nullptr, hni, NN, 64, 256);
    gemm4<<<(tn + 255) / 256, 256, 0, stream>>>(hc, Wnj_l, nullptr, hnj, NN, 64, 256);
    gemm4<<<(tn + 255) / 256, 256, 0, stream>>>(hc, Wnd_l, bnd_l,  hpj, NN, 64, 256);
    edge_kernel<<<NE / EPB, 256, 0, stream>>>(fc, hni, hnj, Wfij_l, be_l, at_l,
                                              src, dst, sc, fn);
    agg_kernel<<<NN / 4, 256, 0, stream>>>(hpj, sc, src, elist, off, hn);
    float* tmp = hc; hc = hn; hn = tmp;
    tmp = fc; fc = fn; fn = tmp;
  }
  gemm4<<<(NN * 16 + 255) / 256, 256, 0, stream>>>(hc, Wf, bf, out, NN, 64, 64);
}

// Round 2
// 960.123 us; speedup vs baseline: 1.1315x; 1.1315x over previous
//
#include <hip/hip_runtime.h>
#include <cmath>

#define NN 20000
#define NE 200000
#define EPB 64          // edges per block in edge kernel (2 rounds of 32)
#define SCAN_BLOCKS 79  // ceil(NN/256)

__device__ __forceinline__ float4 ld4(const float* p){ return *(const float4*)p; }

// RNE float->bf16 (bit-exact with np/jax bfloat16 rounding for normal values)
__device__ __forceinline__ unsigned int packbf(float a, float b) {
  unsigned int ua = __float_as_uint(a);
  unsigned int ub = __float_as_uint(b);
  ua = (ua + 0x7fffu + ((ua >> 16) & 1u)) >> 16;
  ub = (ub + 0x7fffu + ((ub >> 16) & 1u)) >> 16;
  return ua | (ub << 16);
}
// unpack 2 packed-bf16 uints -> 4 floats (exact: bf16->f32 is a 16-bit shift)
__device__ __forceinline__ float4 up4(uint2 u) {
  return make_float4(__uint_as_float(u.x << 16), __uint_as_float(u.x & 0xffff0000u),
                     __uint_as_float(u.y << 16), __uint_as_float(u.y & 0xffff0000u));
}

// O[m][j] = sum_k A[m][k]*B[k][j] + bias[j]; one thread per 4 consecutive j (f32 out)
__global__ void gemm4(const float* __restrict__ A, const float* __restrict__ B,
                      const float* __restrict__ bias, float* __restrict__ O,
                      int M, int K, int Nout) {
  int jt = Nout >> 2;
  int idx = blockIdx.x * 256 + threadIdx.x;
  if (idx >= M * jt) return;
  int m = idx / jt;
  int j4 = (idx - m * jt) << 2;
  const float* a = A + (long)m * K;
  const float* b = B + j4;
  float ax = 0.f, ay = 0.f, az = 0.f, aw = 0.f;
  for (int k = 0; k < K; k++) {
    float av = a[k];
    float4 bv = ld4(b + (long)k * Nout);
    ax = fmaf(av, bv.x, ax); ay = fmaf(av, bv.y, ay);
    az = fmaf(av, bv.z, az); aw = fmaf(av, bv.w, aw);
  }
  if (bias) { float4 bb = ld4(bias + j4); ax += bb.x; ay += bb.y; az += bb.z; aw += bb.w; }
  *(float4*)(O + (long)m * Nout + j4) = make_float4(ax, ay, az, aw);
}

// Same but output packed bf16 (uint2 = 4 channels)
__global__ void gemm4_bf16(const float* __restrict__ A, const float* __restrict__ B,
                           const float* __restrict__ bias, uint2* __restrict__ O,
                           int M, int K, int Nout) {
  int jt = Nout >> 2;
  int idx = blockIdx.x * 256 + threadIdx.x;
  if (idx >= M * jt) return;
  int m = idx / jt;
  int j4 = (idx - m * jt) << 2;
  const float* a = A + (long)m * K;
  const float* b = B + j4;
  float ax = 0.f, ay = 0.f, az = 0.f, aw = 0.f;
  for (int k = 0; k < K; k++) {
    float av = a[k];
    float4 bv = ld4(b + (long)k * Nout);
    ax = fmaf(av, bv.x, ax); ay = fmaf(av, bv.y, ay);
    az = fmaf(av, bv.z, az); aw = fmaf(av, bv.w, aw);
  }
  if (bias) { float4 bb = ld4(bias + j4); ax += bb.x; ay += bb.y; az += bb.z; aw += bb.w; }
  O[(long)m * jt + (j4 >> 2)] = make_uint2(packbf(ax, ay), packbf(az, aw));
}

__global__ void zero_i32(int* __restrict__ p, int n) {
  int i = blockIdx.x * 256 + threadIdx.x;
  if (i < n) p[i] = 0;
}

__global__ void count_deg(const int* __restrict__ dst, int* __restrict__ deg) {
  int e = blockIdx.x * 256 + threadIdx.x;
  if (e < NE) atomicAdd(&deg[dst[e]], 1);
}

// multi-block scan: per-block exclusive scan + block sums
__global__ void scan1(const int* __restrict__ deg, int* __restrict__ off, int* __restrict__ bsum) {
  __shared__ int buf[256];
  int t = threadIdx.x;
  int g = blockIdx.x * 256 + t;
  int v = (g < NN) ? deg[g] : 0;
  buf[t] = v;
  __syncthreads();
  for (int s = 1; s < 256; s <<= 1) {
    int x = (t >= s) ? buf[t - s] : 0;
    __syncthreads();
    buf[t] += x;
    __syncthreads();
  }
  if (g < NN) off[g] = buf[t] - v;
  if (t == 255) bsum[blockIdx.x] = buf[255];
}

__global__ void scan2(int* __restrict__ bsum, int* __restrict__ off) {
  __shared__ int buf[128];
  int t = threadIdx.x;
  int v = (t < SCAN_BLOCKS) ? bsum[t] : 0;
  buf[t] = v;
  __syncthreads();
  for (int s = 1; s < 128; s <<= 1) {
    int x = (t >= s) ? buf[t - s] : 0;
    __syncthreads();
    buf[t] += x;
    __syncthreads();
  }
  if (t < SCAN_BLOCKS) bsum[t] = buf[t] - v;   // exclusive block prefix
  if (t == 127) off[NN] = buf[127];            // total (=NE)
}

__global__ void scan3(int* __restrict__ off, const int* __restrict__ bsum) {
  int g = blockIdx.x * 256 + threadIdx.x;
  if (g < NN) off[g] += bsum[blockIdx.x];
}

__global__ void fill_csr(const int* __restrict__ dst, const int* __restrict__ off,
                         int* __restrict__ cursor, int* __restrict__ elist) {
  int e = blockIdx.x * 256 + threadIdx.x;
  if (e >= NE) return;
  int d = dst[e];
  int p = atomicAdd(&cursor[d], 1);
  elist[off[d] + p] = e;
}

// Fused edge pass: f_out = hni[src]+hnj[dst]+f@Wfij+bias ; scores ; f-update
// hni/hnj are bf16-packed rows (64 uint2 = 256 ch). W staged in LDS as bf16 (32KB).
// One wave handles 8 edges; lane c owns channels 4c..4c+3 (head = c>>4).
__global__ __launch_bounds__(256) void edge_kernel(
    const float* __restrict__ f_cur, const uint2* __restrict__ hni,
    const uint2* __restrict__ hnj, const float* __restrict__ Wf_l,
    const float* __restrict__ be_l, const float* __restrict__ attn_l,
    const int* __restrict__ src, const int* __restrict__ dst,
    float* __restrict__ score, float* __restrict__ f_next)
{
  __shared__ unsigned int Wsh[64 * 128];   // bf16-pair packed, 32 KB
  int t = threadIdx.x;
  #pragma unroll
  for (int v = 0; v < 16; v++) {
    int o = t * 4 + v * 1024;              // f32 element index (multiple of 4)
    float4 wv = ld4(Wf_l + o);
    Wsh[(o >> 1)]     = packbf(wv.x, wv.y);
    Wsh[(o >> 1) + 1] = packbf(wv.z, wv.w);
  }
  __syncthreads();
  int lane = t & 63, wv = t >> 6;
  float4 bias4 = ld4(be_l + 4 * lane);
  float4 attn4 = ld4(attn_l + 4 * lane);
  int base = blockIdx.x * EPB + wv * 8;
  for (int r = 0; r < EPB / 32; r++) {
    int ew = base + r * 32;
    float4 acc[8];
    #pragma unroll
    for (int i = 0; i < 8; i++) {
      int e = ew + i;
      int s = src[e]; int d = dst[e];
      float4 a = up4(hni[(long)s * 64 + lane]);
      float4 b = up4(hnj[(long)d * 64 + lane]);
      acc[i].x = a.x + b.x + bias4.x;
      acc[i].y = a.y + b.y + bias4.y;
      acc[i].z = a.z + b.z + bias4.z;
      acc[i].w = a.w + b.w + bias4.w;
    }
    const float* frow = f_cur + (long)ew * 64;
    #pragma unroll 2
    for (int k = 0; k < 64; k += 4) {
      float4 w0 = up4(*(const uint2*)&Wsh[(k + 0) * 128 + 2 * lane]);
      float4 w1 = up4(*(const uint2*)&Wsh[(k + 1) * 128 + 2 * lane]);
      float4 w2 = up4(*(const uint2*)&Wsh[(k + 2) * 128 + 2 * lane]);
      float4 w3 = up4(*(const uint2*)&Wsh[(k + 3) * 128 + 2 * lane]);
      #pragma unroll
      for (int i = 0; i < 8; i++) {
        float4 fv = ld4(frow + i * 64 + k);   // wave-uniform, L1-hot
        acc[i].x = fmaf(fv.x, w0.x, acc[i].x); acc[i].y = fmaf(fv.x, w0.y, acc[i].y);
        acc[i].z = fmaf(fv.x, w0.z, acc[i].z); acc[i].w = fmaf(fv.x, w0.w, acc[i].w);
        acc[i].x = fmaf(fv.y, w1.x, acc[i].x); acc[i].y = fmaf(fv.y, w1.y, acc[i].y);
        acc[i].z = fmaf(fv.y, w1.z, acc[i].z); acc[i].w = fmaf(fv.y, w1.w, acc[i].w);
        acc[i].x = fmaf(fv.z, w2.x, acc[i].x); acc[i].y = fmaf(fv.z, w2.y, acc[i].y);
        acc[i].z = fmaf(fv.z, w2.z, acc[i].z); acc[i].w = fmaf(fv.z, w2.w, acc[i].w);
        acc[i].x = fmaf(fv.w, w3.x, acc[i].x); acc[i].y = fmaf(fv.w, w3.y, acc[i].y);
        acc[i].z = fmaf(fv.w, w3.z, acc[i].z); acc[i].w = fmaf(fv.w, w3.w, acc[i].w);
      }
    }
    #pragma unroll
    for (int i = 0; i < 8; i++) {
      int e = ew + i;
      float4 fo = acc[i];
      // leaky-relu + attention score (reduce within 16-lane head group)
      float lx = fo.x > 0.f ? fo.x : 0.01f * fo.x;
      float ly = fo.y > 0.f ? fo.y : 0.01f * fo.y;
      float lz = fo.z > 0.f ? fo.z : 0.01f * fo.z;
      float lw = fo.w > 0.f ? fo.w : 0.01f * fo.w;
      float part = lx * attn4.x + ly * attn4.y + lz * attn4.z + lw * attn4.w;
      part += __shfl_xor(part, 1);
      part += __shfl_xor(part, 2);
      part += __shfl_xor(part, 4);
      part += __shfl_xor(part, 8);
      if ((lane & 15) == 0) score[e * 4 + (lane >> 4)] = part;
      // f update: head-mean -> InstanceNorm -> ELU  (uses pre-activation fo)
      float vx = fo.x, vy = fo.y, vz = fo.z, vw = fo.w;
      vx += __shfl_xor(vx, 16); vy += __shfl_xor(vy, 16); vz += __shfl_xor(vz, 16); vw += __shfl_xor(vw, 16);
      vx += __shfl_xor(vx, 32); vy += __shfl_xor(vy, 32); vz += __shfl_xor(vz, 32); vw += __shfl_xor(vw, 32);
      vx *= 0.25f; vy *= 0.25f; vz *= 0.25f; vw *= 0.25f;
      float s1 = vx + vy + vz + vw;
      float s2 = vx * vx + vy * vy + vz * vz + vw * vw;
      s1 += __shfl_xor(s1, 1); s2 += __shfl_xor(s2, 1);
      s1 += __shfl_xor(s1, 2); s2 += __shfl_xor(s2, 2);
      s1 += __shfl_xor(s1, 4); s2 += __shfl_xor(s2, 4);
      s1 += __shfl_xor(s1, 8); s2 += __shfl_xor(s2, 8);
      float mean = s1 * 0.015625f;
      float var  = s2 * 0.015625f - mean * mean;
      float rs = rsqrtf(var + 1e-5f);
      if (lane < 16) {
        float ox = (vx - mean) * rs; ox = ox > 0.f ? ox : expm1f(ox);
        float oy = (vy - mean) * rs; oy = oy > 0.f ? oy : expm1f(oy);
        float oz = (vz - mean) * rs; oz = oz > 0.f ? oz : expm1f(oz);
        float ow = (vw - mean) * rs; ow = ow > 0.f ? ow : expm1f(ow);
        *(float4*)(f_next + (long)e * 64 + 4 * lane) = make_float4(ox, oy, oz, ow);
      }
    }
  }
}

// One wave per dst node: softmax over incoming edges + weighted hproj[src] sum
// + head-mean + InstanceNorm + ELU. hproj is bf16-packed.
__global__ __launch_bounds__(256) void agg_kernel(
    const uint2* __restrict__ hproj, const float* __restrict__ score,
    const int* __restrict__ src, const int* __restrict__ elist,
    const int* __restrict__ off, float* __restrict__ h_next)
{
  int gw = (blockIdx.x * 256 + threadIdx.x) >> 6;
  int lane = threadIdx.x & 63;
  if (gw >= NN) return;
  int o0 = off[gw], o1 = off[gw + 1];
  int hh = lane >> 4;
  if (o0 == o1) {
    if (lane < 16) *(float4*)(h_next + (long)gw * 64 + 4 * lane) = make_float4(0.f, 0.f, 0.f, 0.f);
    return;
  }
  float mx = -3.0e38f;
  for (int i = o0; i < o1; i++) {
    int e = elist[i];
    mx = fmaxf(mx, score[e * 4 + hh]);
  }
  float ax = 0.f, ay = 0.f, az = 0.f, aw = 0.f, den = 0.f;
  for (int i = o0; i < o1; i++) {
    int e = elist[i];
    float w = __expf(score[e * 4 + hh] - mx);
    den += w;
    float4 hp = up4(hproj[(long)src[e] * 64 + lane]);
    ax = fmaf(w, hp.x, ax); ay = fmaf(w, hp.y, ay);
    az = fmaf(w, hp.z, az); aw = fmaf(w, hp.w, aw);
  }
  float inv = 1.f / den;
  float vx = ax * inv, vy = ay * inv, vz = az * inv, vw = aw * inv;
  vx += __shfl_xor(vx, 16); vy += __shfl_xor(vy, 16); vz += __shfl_xor(vz, 16); vw += __shfl_xor(vw, 16);
  vx += __shfl_xor(vx, 32); vy += __shfl_xor(vy, 32); vz += __shfl_xor(vz, 32); vw += __shfl_xor(vw, 32);
  vx *= 0.25f; vy *= 0.25f; vz *= 0.25f; vw *= 0.25f;
  float s1 = vx + vy + vz + vw;
  float s2 = vx * vx + vy * vy + vz * vz + vw * vw;
  s1 += __shfl_xor(s1, 1); s2 += __shfl_xor(s2, 1);
  s1 += __shfl_xor(s1, 2); s2 += __shfl_xor(s2, 2);
  s1 += __shfl_xor(s1, 4); s2 += __shfl_xor(s2, 4);
  s1 += __shfl_xor(s1, 8); s2 += __shfl_xor(s2, 8);
  float mean = s1 * 0.015625f;
  float var  = s2 * 0.015625f - mean * mean;
  float rs = rsqrtf(var + 1e-5f);
  if (lane < 16) {
    float ox = (vx - mean) * rs; ox = ox > 0.f ? ox : expm1f(ox);
    float oy = (vy - mean) * rs; oy = oy > 0.f ? oy : expm1f(oy);
    float oz = (vz - mean) * rs; oz = oz > 0.f ? oz : expm1f(oz);
    float ow = (vw - mean) * rs; ow = ow > 0.f ? ow : expm1f(ow);
    *(float4*)(h_next + (long)gw * 64 + 4 * lane) = make_float4(ox, oy, oz, ow);
  }
}

extern "C" void kernel_launch(void* const* d_in, const int* in_sizes, int n_in,
                              void* d_out, int out_size, void* d_ws, size_t ws_size,
                              hipStream_t stream) {
  const float* x      = (const float*)d_in[0];
  const float* efeat  = (const float*)d_in[1];
  const int*   src    = (const int*)d_in[2];
  const int*   dst    = (const int*)d_in[3];
  const float* Wn0    = (const float*)d_in[4];
  const float* bn0    = (const float*)d_in[5];
  const float* We0    = (const float*)d_in[6];
  const float* be0    = (const float*)d_in[7];
  const float* Wnode  = (const float*)d_in[8];
  const float* bnode  = (const float*)d_in[9];
  const float* Wni    = (const float*)d_in[10];
  const float* Wnj    = (const float*)d_in[11];
  const float* Wfij   = (const float*)d_in[12];
  const float* attn   = (const float*)d_in[13];
  const float* bias_e = (const float*)d_in[14];
  const float* Wf     = (const float*)d_in[15];
  const float* bf     = (const float*)d_in[16];
  float* out = (float*)d_out;

  char* w = (char*)d_ws;
  auto alloc = [&](size_t nbytes) { char* p = w; w += (nbytes + 255) & ~(size_t)255; return p; };
  float* h_a  = (float*)alloc((size_t)NN * 64 * 4);
  float* h_b  = (float*)alloc((size_t)NN * 64 * 4);
  float* f_a  = (float*)alloc((size_t)NE * 64 * 4);
  float* f_b  = (float*)alloc((size_t)NE * 64 * 4);
  uint2* hni  = (uint2*)alloc((size_t)NN * 256 * 2);   // bf16 packed
  uint2* hnj  = (uint2*)alloc((size_t)NN * 256 * 2);
  uint2* hpj  = (uint2*)alloc((size_t)NN * 256 * 2);
  float* sc   = (float*)alloc((size_t)NE * 4 * 4);
  int* deg    = (int*)alloc((size_t)NN * 2 * 4);       // deg + cursor contiguous
  int* cursor = deg + NN;
  int* off    = (int*)alloc((size_t)(NN + 1) * 4);
  int* elist  = (int*)alloc((size_t)NE * 4);
  int* bsum   = (int*)alloc((size_t)128 * 4);

  // input projections
  gemm4<<<(NN * 16 + 255) / 256, 256, 0, stream>>>(x, Wn0, bn0, h_a, NN, 65, 64);
  gemm4<<<(NE * 16 + 255) / 256, 256, 0, stream>>>(efeat, We0, be0, f_a, NE, 15, 64);

  // CSR over dst (multi-block scan)
  zero_i32<<<(2 * NN + 255) / 256, 256, 0, stream>>>(deg, 2 * NN);
  count_deg<<<(NE + 255) / 256, 256, 0, stream>>>(dst, deg);
  scan1<<<SCAN_BLOCKS, 256, 0, stream>>>(deg, off, bsum);
  scan2<<<1, 128, 0, stream>>>(bsum, off);
  scan3<<<SCAN_BLOCKS, 256, 0, stream>>>(off, bsum);
  fill_csr<<<(NE + 255) / 256, 256, 0, stream>>>(dst, off, cursor, elist);

  float* hc = h_a; float* hn = h_b;
  float* fc = f_a; float* fn = f_b;
  for (int l = 0; l < 2; l++) {
    const float* Wni_l  = Wni  + (size_t)l * 64 * 256;
    const float* Wnj_l  = Wnj  + (size_t)l * 64 * 256;
    const float* Wnd_l  = Wnode + (size_t)l * 64 * 256;
    const float* Wfij_l = Wfij + (size_t)l * 64 * 256;
    const float* bnd_l  = bnode + (size_t)l * 256;
    const float* be_l   = bias_e + (size_t)l * 256;
    const float* at_l   = attn + (size_t)l * 256;
    int tn = NN * 64;  // M*(Nout/4) threads for Nout=256
    gemm4_bf16<<<(tn + 255) / 256, 256, 0, stream>>>(hc, Wni_l, nullptr, hni, NN, 64, 256);
    gemm4_bf16<<<(tn + 255) / 256, 256, 0, stream>>>(hc, Wnj_l, nullptr, hnj, NN, 64, 256);
    gemm4_bf16<<<(tn + 255) / 256, 256, 0, stream>>>(hc, Wnd_l, bnd_l,  hpj, NN, 64, 256);
    edge_kernel<<<NE / EPB, 256, 0, stream>>>(fc, hni, hnj, Wfij_l, be_l, at_l,
                                              src, dst, sc, fn);
    agg_kernel<<<NN / 4, 256, 0, stream>>>(hpj, sc, src, elist, off, hn);
    float* tmp = hc; hc = hn; hn = tmp;
    tmp = fc; fc = fn; fn = tmp;
  }
  gemm4<<<(NN * 16 + 255) / 256, 256, 0, stream>>>(hc, Wf, bf, out, NN, 64, 64);
}

// Round 3
// 611.348 us; speedup vs baseline: 1.7770x; 1.5705x over previous
//
#include <hip/hip_runtime.h>
#include <cmath>

#define NN 20000
#define NE 200000
#define SCAN_BLOCKS 79  // ceil(NN/256)

typedef __attribute__((ext_vector_type(8))) short bf16x8;
typedef __attribute__((ext_vector_type(4))) float f32x4;
typedef unsigned int uint;

__device__ __forceinline__ float4 ld4(const float* p){ return *(const float4*)p; }

// RNE float->bf16
__device__ __forceinline__ uint packbf(float a, float b) {
  uint ua = __float_as_uint(a);
  uint ub = __float_as_uint(b);
  ua = (ua + 0x7fffu + ((ua >> 16) & 1u)) >> 16;
  ub = (ub + 0x7fffu + ((ub >> 16) & 1u)) >> 16;
  return ua | (ub << 16);
}
__device__ __forceinline__ float4 up4(uint2 u) {
  return make_float4(__uint_as_float(u.x << 16), __uint_as_float(u.x & 0xffff0000u),
                     __uint_as_float(u.y << 16), __uint_as_float(u.y & 0xffff0000u));
}

// naive GEMM -> packed bf16 out. O[m][j]=sum_k A[m][k]B[k][j]+bias[j]
__global__ void gemm4_bf16(const float* __restrict__ A, const float* __restrict__ B,
                           const float* __restrict__ bias, uint2* __restrict__ O,
                           int M, int K, int Nout) {
  int jt = Nout >> 2;
  int idx = blockIdx.x * 256 + threadIdx.x;
  if (idx >= M * jt) return;
  int m = idx / jt;
  int j4 = (idx - m * jt) << 2;
  const float* a = A + (long)m * K;
  const float* b = B + j4;
  float ax = 0.f, ay = 0.f, az = 0.f, aw = 0.f;
  for (int k = 0; k < K; k++) {
    float av = a[k];
    float4 bv = ld4(b + (long)k * Nout);
    ax = fmaf(av, bv.x, ax); ay = fmaf(av, bv.y, ay);
    az = fmaf(av, bv.z, az); aw = fmaf(av, bv.w, aw);
  }
  if (bias) { float4 bb = ld4(bias + j4); ax += bb.x; ay += bb.y; az += bb.z; aw += bb.w; }
  O[(long)m * jt + (j4 >> 2)] = make_uint2(packbf(ax, ay), packbf(az, aw));
}

__global__ void zero_i32(int* __restrict__ p, int n) {
  int i = blockIdx.x * 256 + threadIdx.x;
  if (i < n) p[i] = 0;
}

__global__ void count_deg(const int* __restrict__ dst, int* __restrict__ deg) {
  int e = blockIdx.x * 256 + threadIdx.x;
  if (e < NE) atomicAdd(&deg[dst[e]], 1);
}

__global__ void scan1(const int* __restrict__ deg, int* __restrict__ off, int* __restrict__ bsum) {
  __shared__ int buf[256];
  int t = threadIdx.x;
  int g = blockIdx.x * 256 + t;
  int v = (g < NN) ? deg[g] : 0;
  buf[t] = v;
  __syncthreads();
  for (int s = 1; s < 256; s <<= 1) {
    int x = (t >= s) ? buf[t - s] : 0;
    __syncthreads();
    buf[t] += x;
    __syncthreads();
  }
  if (g < NN) off[g] = buf[t] - v;
  if (t == 255) bsum[blockIdx.x] = buf[255];
}

__global__ void scan2(int* __restrict__ bsum, int* __restrict__ off) {
  __shared__ int buf[128];
  int t = threadIdx.x;
  int v = (t < SCAN_BLOCKS) ? bsum[t] : 0;
  buf[t] = v;
  __syncthreads();
  for (int s = 1; s < 128; s <<= 1) {
    int x = (t >= s) ? buf[t - s] : 0;
    __syncthreads();
    buf[t] += x;
    __syncthreads();
  }
  if (t < SCAN_BLOCKS) bsum[t] = buf[t] - v;
  if (t == 127) off[NN] = buf[127];
}

__global__ void scan3(int* __restrict__ off, const int* __restrict__ bsum) {
  int g = blockIdx.x * 256 + threadIdx.x;
  if (g < NN) off[g] += bsum[blockIdx.x];
}

__global__ void fill_csr(const int* __restrict__ dst, const int* __restrict__ off,
                         int* __restrict__ cursor, int* __restrict__ elist) {
  int e = blockIdx.x * 256 + threadIdx.x;
  if (e >= NE) return;
  int d = dst[e];
  int p = atomicAdd(&cursor[d], 1);
  elist[off[d] + p] = e;
}

// Build transposed bf16 weights: WtF[l][c][k] from Wfij[l][k][c] (c<256),
// Wt3[l][c3][k] from {Wni,Wnj,Wnode}[l][k][c3&255] (c3<768). One thread per row.
__global__ void prep_w(const float* __restrict__ Wfij, const float* __restrict__ Wni,
                       const float* __restrict__ Wnj, const float* __restrict__ Wnode,
                       uint* __restrict__ WtF, uint* __restrict__ Wt3) {
  int rid = blockIdx.x * 256 + threadIdx.x;
  if (rid >= 2048) return;
  int l = rid >> 10, r = rid & 1023;
  const float* S; uint* D; int c;
  if (r < 256) { S = Wfij + l * 16384; c = r; D = WtF + l * 8192 + r * 32; }
  else {
    int c3 = r - 256; int arr = c3 >> 8; c = c3 & 255;
    S = (arr == 0 ? Wni : arr == 1 ? Wnj : Wnode) + l * 16384;
    D = Wt3 + l * 24576 + c3 * 32;
  }
  for (int k8 = 0; k8 < 8; k8++) {
    uint u0 = packbf(S[(k8*8+0)*256 + c], S[(k8*8+1)*256 + c]);
    uint u1 = packbf(S[(k8*8+2)*256 + c], S[(k8*8+3)*256 + c]);
    uint u2 = packbf(S[(k8*8+4)*256 + c], S[(k8*8+5)*256 + c]);
    uint u3 = packbf(S[(k8*8+6)*256 + c], S[(k8*8+7)*256 + c]);
    *((uint4*)(D + k8 * 4)) = make_uint4(u0, u1, u2, u3);
  }
}

// MFMA node projections: D[c3][n] = sum_k Wt3[c3][k] h[n][k]  (c3 in 768 = ni|nj|node)
// block: 4 waves split channels (192 each), 2 chunks of 16 nodes.
__global__ __launch_bounds__(256) void proj_mfma(
    const uint4* __restrict__ h_bf, const uint4* __restrict__ Wt3_l,
    const float* __restrict__ bnd_l,
    uint2* __restrict__ hni, uint2* __restrict__ hnj, uint2* __restrict__ hpj)
{
  int t = threadIdx.x, lane = t & 63, w = t >> 6;
  int col = lane & 15, quad = lane >> 4;
  for (int ch = 0; ch < 2; ch++) {
    int n = blockIdx.x * 32 + ch * 16 + col;
    bf16x8 b0 = *(const bf16x8*)&h_bf[(long)n * 8 + quad];
    bf16x8 b1 = *(const bf16x8*)&h_bf[(long)n * 8 + 4 + quad];
    f32x4 acc[12];
    #pragma unroll
    for (int ct = 0; ct < 12; ct++) acc[ct] = (f32x4){0.f, 0.f, 0.f, 0.f};
    #pragma unroll
    for (int ct = 0; ct < 12; ct++) {
      int cg = w * 192 + ct * 16 + col;
      bf16x8 a0 = *(const bf16x8*)&Wt3_l[(long)cg * 8 + quad];
      bf16x8 a1 = *(const bf16x8*)&Wt3_l[(long)cg * 8 + 4 + quad];
      acc[ct] = __builtin_amdgcn_mfma_f32_16x16x32_bf16(a0, b0, acc[ct], 0, 0, 0);
      acc[ct] = __builtin_amdgcn_mfma_f32_16x16x32_bf16(a1, b1, acc[ct], 0, 0, 0);
    }
    #pragma unroll
    for (int ct = 0; ct < 12; ct++) {
      int cg0 = w * 192 + ct * 16 + quad * 4;
      int arr = cg0 >> 8;
      int c = cg0 & 255;
      float x0 = acc[ct][0], x1 = acc[ct][1], x2 = acc[ct][2], x3 = acc[ct][3];
      if (arr == 2) { float4 bb = ld4(bnd_l + c); x0 += bb.x; x1 += bb.y; x2 += bb.z; x3 += bb.w; }
      uint2* dp = arr == 0 ? hni : arr == 1 ? hnj : hpj;
      dp[(long)n * 64 + (c >> 2)] = make_uint2(packbf(x0, x1), packbf(x2, x3));
    }
  }
}

// MFMA fused edge pass. D[c][e] = (f@Wfij)[e][c] via mfma(A=Wt, B=f^T).
// Lane (quad,col) holds channels {ct*16+quad*4+r} of edge base+col -> lane-local epilogue.
__global__ __launch_bounds__(256) void edge_mfma(
    const uint4* __restrict__ f_bf, const uint2* __restrict__ hni,
    const uint2* __restrict__ hnj, const uint4* __restrict__ WtF_l,
    const float* __restrict__ be_l, const float* __restrict__ attn_l,
    const int* __restrict__ src, const int* __restrict__ dst,
    float* __restrict__ score, uint2* __restrict__ f_next)
{
  __shared__ uint Wsh[256 * 36];   // rows padded to 72 bf16 (36 dw): 2-way conflicts only
  int t = threadIdx.x;
  #pragma unroll
  for (int i = 0; i < 8; i++) {
    int g = t + i * 256;
    int c = g >> 3, pos = g & 7;
    uint4 v = WtF_l[c * 8 + pos];
    *((uint4*)&Wsh[c * 36 + pos * 4]) = v;
  }
  __syncthreads();
  int lane = t & 63, w = t >> 6;
  int col = lane & 15, quad = lane >> 4;
  for (int ch = 0; ch < 5; ch++) {
    int e = blockIdx.x * 320 + ch * 64 + w * 16 + col;
    bf16x8 b0 = *(const bf16x8*)&f_bf[(long)e * 8 + quad];
    bf16x8 b1 = *(const bf16x8*)&f_bf[(long)e * 8 + 4 + quad];
    f32x4 acc[16];
    #pragma unroll
    for (int ct = 0; ct < 16; ct++) acc[ct] = (f32x4){0.f, 0.f, 0.f, 0.f};
    #pragma unroll
    for (int ct = 0; ct < 16; ct++) {
      int c = ct * 16 + col;
      bf16x8 a0 = *((const bf16x8*)&Wsh[c * 36 + quad * 4]);
      bf16x8 a1 = *((const bf16x8*)&Wsh[c * 36 + 16 + quad * 4]);
      acc[ct] = __builtin_amdgcn_mfma_f32_16x16x32_bf16(a0, b0, acc[ct], 0, 0, 0);
      acc[ct] = __builtin_amdgcn_mfma_f32_16x16x32_bf16(a1, b1, acc[ct], 0, 0, 0);
    }
    int s_ = src[e], d_ = dst[e];
    const uint2* ni = hni + (long)s_ * 64;
    const uint2* nj = hnj + (long)d_ * 64;
    float fo[16][4];
    float sh[4] = {0.f, 0.f, 0.f, 0.f};
    #pragma unroll
    for (int ct = 0; ct < 16; ct++) {
      int c = ct * 16 + quad * 4;
      float4 a = up4(ni[ct * 4 + quad]);
      float4 b = up4(nj[ct * 4 + quad]);
      float4 bb = ld4(be_l + c);
      float4 at = ld4(attn_l + c);
      float x0 = acc[ct][0] + a.x + b.x + bb.x;
      float x1 = acc[ct][1] + a.y + b.y + bb.y;
      float x2 = acc[ct][2] + a.z + b.z + bb.z;
      float x3 = acc[ct][3] + a.w + b.w + bb.w;
      fo[ct][0] = x0; fo[ct][1] = x1; fo[ct][2] = x2; fo[ct][3] = x3;
      float l0 = x0 > 0.f ? x0 : 0.01f * x0;
      float l1 = x1 > 0.f ? x1 : 0.01f * x1;
      float l2 = x2 > 0.f ? x2 : 0.01f * x2;
      float l3 = x3 > 0.f ? x3 : 0.01f * x3;
      sh[ct >> 2] += l0 * at.x + l1 * at.y + l2 * at.z + l3 * at.w;
    }
    #pragma unroll
    for (int h = 0; h < 4; h++) {
      sh[h] += __shfl_xor(sh[h], 16);
      sh[h] += __shfl_xor(sh[h], 32);
    }
    float sv = quad == 0 ? sh[0] : quad == 1 ? sh[1] : quad == 2 ? sh[2] : sh[3];
    score[e * 4 + quad] = sv;
    // head mean (lane-local: heads are ct>>2, c64 = (ct&3)*16 + quad*4 + r)
    float mj[4][4];
    float s1 = 0.f, s2 = 0.f;
    #pragma unroll
    for (int j = 0; j < 4; j++) {
      #pragma unroll
      for (int r = 0; r < 4; r++) {
        float m = 0.25f * (fo[j][r] + fo[4 + j][r] + fo[8 + j][r] + fo[12 + j][r]);
        mj[j][r] = m;
        s1 += m; s2 += m * m;
      }
    }
    s1 += __shfl_xor(s1, 16); s2 += __shfl_xor(s2, 16);
    s1 += __shfl_xor(s1, 32); s2 += __shfl_xor(s2, 32);
    float mean = s1 * 0.015625f;
    float var  = s2 * 0.015625f - mean * mean;
    float rs = rsqrtf(var + 1e-5f);
    #pragma unroll
    for (int j = 0; j < 4; j++) {
      float o0 = (mj[j][0] - mean) * rs; o0 = o0 > 0.f ? o0 : expm1f(o0);
      float o1 = (mj[j][1] - mean) * rs; o1 = o1 > 0.f ? o1 : expm1f(o1);
      float o2 = (mj[j][2] - mean) * rs; o2 = o2 > 0.f ? o2 : expm1f(o2);
      float o3 = (mj[j][3] - mean) * rs; o3 = o3 > 0.f ? o3 : expm1f(o3);
      f_next[(long)e * 16 + j * 4 + quad] = make_uint2(packbf(o0, o1), packbf(o2, o3));
    }
  }
}

// One wave per dst node: softmax + weighted hproj[src] sum + head-mean + inorm + ELU.
__global__ __launch_bounds__(256) void agg_kernel(
    const uint2* __restrict__ hproj, const float* __restrict__ score,
    const int* __restrict__ src, const int* __restrict__ elist,
    const int* __restrict__ off, uint2* __restrict__ h_next)
{
  int gw = (blockIdx.x * 256 + threadIdx.x) >> 6;
  int lane = threadIdx.x & 63;
  if (gw >= NN) return;
  int o0 = off[gw], o1 = off[gw + 1];
  int hh = lane >> 4;
  if (o0 == o1) {
    if (lane < 16) h_next[(long)gw * 16 + lane] = make_uint2(0u, 0u);
    return;
  }
  float mx = -3.0e38f;
  for (int i = o0; i < o1; i++) {
    int e = elist[i];
    mx = fmaxf(mx, score[e * 4 + hh]);
  }
  float ax = 0.f, ay = 0.f, az = 0.f, aw = 0.f, den = 0.f;
  for (int i = o0; i < o1; i++) {
    int e = elist[i];
    float wgt = __expf(score[e * 4 + hh] - mx);
    den += wgt;
    float4 hp = up4(hproj[(long)src[e] * 64 + lane]);
    ax = fmaf(wgt, hp.x, ax); ay = fmaf(wgt, hp.y, ay);
    az = fmaf(wgt, hp.z, az); aw = fmaf(wgt, hp.w, aw);
  }
  float inv = 1.f / den;
  float vx = ax * inv, vy = ay * inv, vz = az * inv, vw = aw * inv;
  vx += __shfl_xor(vx, 16); vy += __shfl_xor(vy, 16); vz += __shfl_xor(vz, 16); vw += __shfl_xor(vw, 16);
  vx += __shfl_xor(vx, 32); vy += __shfl_xor(vy, 32); vz += __shfl_xor(vz, 32); vw += __shfl_xor(vw, 32);
  vx *= 0.25f; vy *= 0.25f; vz *= 0.25f; vw *= 0.25f;
  float s1 = vx + vy + vz + vw;
  float s2 = vx * vx + vy * vy + vz * vz + vw * vw;
  s1 += __shfl_xor(s1, 1); s2 += __shfl_xor(s2, 1);
  s1 += __shfl_xor(s1, 2); s2 += __shfl_xor(s2, 2);
  s1 += __shfl_xor(s1, 4); s2 += __shfl_xor(s2, 4);
  s1 += __shfl_xor(s1, 8); s2 += __shfl_xor(s2, 8);
  float mean = s1 * 0.015625f;
  float var  = s2 * 0.015625f - mean * mean;
  float rs = rsqrtf(var + 1e-5f);
  if (lane < 16) {
    float ox = (vx - mean) * rs; ox = ox > 0.f ? ox : expm1f(ox);
    float oy = (vy - mean) * rs; oy = oy > 0.f ? oy : expm1f(oy);
    float oz = (vz - mean) * rs; oz = oz > 0.f ? oz : expm1f(oz);
    float ow = (vw - mean) * rs; ow = ow > 0.f ? ow : expm1f(ow);
    h_next[(long)gw * 16 + lane] = make_uint2(packbf(ox, oy), packbf(oz, ow));
  }
}

// out[m][j] = sum_k bf16(h)[m][k] * Wf[k][j] + bf[j]
__global__ void final_gemm(const uint2* __restrict__ h, const float* __restrict__ Wf,
                           const float* __restrict__ bf_, float* __restrict__ out) {
  int idx = blockIdx.x * 256 + threadIdx.x;
  if (idx >= NN * 16) return;
  int m = idx >> 4, j4 = (idx & 15) << 2;
  const uint2* row = h + (long)m * 16;
  float ax = 0.f, ay = 0.f, az = 0.f, aw = 0.f;
  for (int kk = 0; kk < 16; kk++) {
    float4 a = up4(row[kk]);
    float4 b0 = ld4(Wf + (kk * 4 + 0) * 64 + j4);
    float4 b1 = ld4(Wf + (kk * 4 + 1) * 64 + j4);
    float4 b2 = ld4(Wf + (kk * 4 + 2) * 64 + j4);
    float4 b3 = ld4(Wf + (kk * 4 + 3) * 64 + j4);
    ax = fmaf(a.x, b0.x, ax); ay = fmaf(a.x, b0.y, ay); az = fmaf(a.x, b0.z, az); aw = fmaf(a.x, b0.w, aw);
    ax = fmaf(a.y, b1.x, ax); ay = fmaf(a.y, b1.y, ay); az = fmaf(a.y, b1.z, az); aw = fmaf(a.y, b1.w, aw);
    ax = fmaf(a.z, b2.x, ax); ay = fmaf(a.z, b2.y, ay); az = fmaf(a.z, b2.z, az); aw = fmaf(a.z, b2.w, aw);
    ax = fmaf(a.w, b3.x, ax); ay = fmaf(a.w, b3.y, ay); az = fmaf(a.w, b3.z, az); aw = fmaf(a.w, b3.w, aw);
  }
  float4 bb = ld4(bf_ + j4);
  *(float4*)(out + (long)m * 64 + j4) = make_float4(ax + bb.x, ay + bb.y, az + bb.z, aw + bb.w);
}

extern "C" void kernel_launch(void* const* d_in, const int* in_sizes, int n_in,
                              void* d_out, int out_size, void* d_ws, size_t ws_size,
                              hipStream_t stream) {
  const float* x      = (const float*)d_in[0];
  const float* efeat  = (const float*)d_in[1];
  const int*   src    = (const int*)d_in[2];
  const int*   dst    = (const int*)d_in[3];
  const float* Wn0    = (const float*)d_in[4];
  const float* bn0    = (const float*)d_in[5];
  const float* We0    = (const float*)d_in[6];
  const float* be0    = (const float*)d_in[7];
  const float* Wnode  = (const float*)d_in[8];
  const float* bnode  = (const float*)d_in[9];
  const float* Wni    = (const float*)d_in[10];
  const float* Wnj    = (const float*)d_in[11];
  const float* Wfij   = (const float*)d_in[12];
  const float* attn   = (const float*)d_in[13];
  const float* bias_e = (const float*)d_in[14];
  const float* Wf     = (const float*)d_in[15];
  const float* bf     = (const float*)d_in[16];
  float* out = (float*)d_out;

  char* w = (char*)d_ws;
  auto alloc = [&](size_t nbytes) { char* p = w; w += (nbytes + 255) & ~(size_t)255; return p; };
  uint2* h_a  = (uint2*)alloc((size_t)NN * 128);   // bf16 [NN][64]
  uint2* h_b  = (uint2*)alloc((size_t)NN * 128);
  uint2* f_a  = (uint2*)alloc((size_t)NE * 128);   // bf16 [NE][64]
  uint2* f_b  = (uint2*)alloc((size_t)NE * 128);
  uint2* hni  = (uint2*)alloc((size_t)NN * 512);   // bf16 [NN][256]
  uint2* hnj  = (uint2*)alloc((size_t)NN * 512);
  uint2* hpj  = (uint2*)alloc((size_t)NN * 512);
  float* sc   = (float*)alloc((size_t)NE * 16);
  uint*  WtF  = (uint*)alloc((size_t)2 * 8192 * 4);    // [2][256][64] bf16
  uint*  Wt3  = (uint*)alloc((size_t)2 * 24576 * 4);   // [2][768][64] bf16
  int* deg    = (int*)alloc((size_t)NN * 2 * 4);
  int* cursor = deg + NN;
  int* off    = (int*)alloc((size_t)(NN + 1) * 4);
  int* elist  = (int*)alloc((size_t)NE * 4);
  int* bsum   = (int*)alloc((size_t)128 * 4);

  // input projections -> bf16
  gemm4_bf16<<<(NN * 16 + 255) / 256, 256, 0, stream>>>(x, Wn0, bn0, h_a, NN, 65, 64);
  gemm4_bf16<<<(NE * 16 + 255) / 256, 256, 0, stream>>>(efeat, We0, be0, f_a, NE, 15, 64);
  prep_w<<<8, 256, 0, stream>>>(Wfij, Wni, Wnj, Wnode, WtF, Wt3);

  // CSR over dst
  zero_i32<<<(2 * NN + 255) / 256, 256, 0, stream>>>(deg, 2 * NN);
  count_deg<<<(NE + 255) / 256, 256, 0, stream>>>(dst, deg);
  scan1<<<SCAN_BLOCKS, 256, 0, stream>>>(deg, off, bsum);
  scan2<<<1, 128, 0, stream>>>(bsum, off);
  scan3<<<SCAN_BLOCKS, 256, 0, stream>>>(off, bsum);
  fill_csr<<<(NE + 255) / 256, 256, 0, stream>>>(dst, off, cursor, elist);

  uint2* hc = h_a; uint2* hn = h_b;
  uint2* fc = f_a; uint2* fn = f_b;
  for (int l = 0; l < 2; l++) {
    const uint4* Wt3_l = (const uint4*)(Wt3 + (size_t)l * 24576);
    const uint4* WtF_l = (const uint4*)(WtF + (size_t)l * 8192);
    const float* bnd_l = bnode + (size_t)l * 256;
    const float* be_l  = bias_e + (size_t)l * 256;
    const float* at_l  = attn + (size_t)l * 256;
    proj_mfma<<<625, 256, 0, stream>>>((const uint4*)hc, Wt3_l, bnd_l, hni, hnj, hpj);
    edge_mfma<<<625, 256, 0, stream>>>((const uint4*)fc, hni, hnj, WtF_l, be_l, at_l,
                                       src, dst, sc, fn);
    agg_kernel<<<NN / 4, 256, 0, stream>>>(hpj, sc, src, elist, off, hn);
    uint2* tmp = hc; hc = hn; hn = tmp;
    tmp = fc; fc = fn; fn = tmp;
  }
  final_gemm<<<(NN * 16 + 255) / 256, 256, 0, stream>>>(hc, Wf, bf, out);
}

// Round 4
// 566.795 us; speedup vs baseline: 1.9166x; 1.0786x over previous
//
#include <hip/hip_runtime.h>
#include <cmath>

#define NN 20000
#define NE 200000
#define SCAN_BLOCKS 79  // ceil(NN/256)

typedef __attribute__((ext_vector_type(8))) short bf16x8;
typedef __attribute__((ext_vector_type(4))) float f32x4;
typedef unsigned int uint;

__device__ __forceinline__ float4 ld4(const float* p){ return *(const float4*)p; }

// RNE float->bf16
__device__ __forceinline__ uint packbf(float a, float b) {
  uint ua = __float_as_uint(a);
  uint ub = __float_as_uint(b);
  ua = (ua + 0x7fffu + ((ua >> 16) & 1u)) >> 16;
  ub = (ub + 0x7fffu + ((ub >> 16) & 1u)) >> 16;
  return ua | (ub << 16);
}
__device__ __forceinline__ float4 up4(uint2 u) {
  return make_float4(__uint_as_float(u.x << 16), __uint_as_float(u.x & 0xffff0000u),
                     __uint_as_float(u.y << 16), __uint_as_float(u.y & 0xffff0000u));
}

// naive GEMM -> packed bf16 out. O[m][j]=sum_k A[m][k]B[k][j]+bias[j]
__global__ void gemm4_bf16(const float* __restrict__ A, const float* __restrict__ B,
                           const float* __restrict__ bias, uint2* __restrict__ O,
                           int M, int K, int Nout) {
  int jt = Nout >> 2;
  int idx = blockIdx.x * 256 + threadIdx.x;
  if (idx >= M * jt) return;
  int m = idx / jt;
  int j4 = (idx - m * jt) << 2;
  const float* a = A + (long)m * K;
  const float* b = B + j4;
  float ax = 0.f, ay = 0.f, az = 0.f, aw = 0.f;
  for (int k = 0; k < K; k++) {
    float av = a[k];
    float4 bv = ld4(b + (long)k * Nout);
    ax = fmaf(av, bv.x, ax); ay = fmaf(av, bv.y, ay);
    az = fmaf(av, bv.z, az); aw = fmaf(av, bv.w, aw);
  }
  if (bias) { float4 bb = ld4(bias + j4); ax += bb.x; ay += bb.y; az += bb.z; aw += bb.w; }
  O[(long)m * jt + (j4 >> 2)] = make_uint2(packbf(ax, ay), packbf(az, aw));
}

__global__ void zero_i32(int* __restrict__ p, int n) {
  int i = blockIdx.x * 256 + threadIdx.x;
  if (i < n) p[i] = 0;
}

__global__ void count_deg(const int* __restrict__ dst, int* __restrict__ deg) {
  int e = blockIdx.x * 256 + threadIdx.x;
  if (e < NE) atomicAdd(&deg[dst[e]], 1);
}

__global__ void scan1(const int* __restrict__ deg, int* __restrict__ off, int* __restrict__ bsum) {
  __shared__ int buf[256];
  int t = threadIdx.x;
  int g = blockIdx.x * 256 + t;
  int v = (g < NN) ? deg[g] : 0;
  buf[t] = v;
  __syncthreads();
  for (int s = 1; s < 256; s <<= 1) {
    int x = (t >= s) ? buf[t - s] : 0;
    __syncthreads();
    buf[t] += x;
    __syncthreads();
  }
  if (g < NN) off[g] = buf[t] - v;
  if (t == 255) bsum[blockIdx.x] = buf[255];
}

__global__ void scan2(int* __restrict__ bsum, int* __restrict__ off) {
  __shared__ int buf[128];
  int t = threadIdx.x;
  int v = (t < SCAN_BLOCKS) ? bsum[t] : 0;
  buf[t] = v;
  __syncthreads();
  for (int s = 1; s < 128; s <<= 1) {
    int x = (t >= s) ? buf[t - s] : 0;
    __syncthreads();
    buf[t] += x;
    __syncthreads();
  }
  if (t < SCAN_BLOCKS) bsum[t] = buf[t] - v;
  if (t == 127) off[NN] = buf[127];
}

__global__ void scan3(int* __restrict__ off, const int* __restrict__ bsum) {
  int g = blockIdx.x * 256 + threadIdx.x;
  if (g < NN) off[g] += bsum[blockIdx.x];
}

__global__ void fill_csr(const int* __restrict__ dst, const int* __restrict__ off,
                         int* __restrict__ cursor, int* __restrict__ elist) {
  int e = blockIdx.x * 256 + threadIdx.x;
  if (e >= NE) return;
  int d = dst[e];
  int p = atomicAdd(&cursor[d], 1);
  elist[off[d] + p] = e;
}

// Build transposed bf16 weights: WtF[l][c][k] from Wfij[l][k][c] (c<256),
// Wt3[l][c3][k] from {Wni,Wnj,Wnode}[l][k][c3&255] (c3<768). One thread per row.
__global__ void prep_w(const float* __restrict__ Wfij, const float* __restrict__ Wni,
                       const float* __restrict__ Wnj, const float* __restrict__ Wnode,
                       uint* __restrict__ WtF, uint* __restrict__ Wt3) {
  int rid = blockIdx.x * 256 + threadIdx.x;
  if (rid >= 2048) return;
  int l = rid >> 10, r = rid & 1023;
  const float* S; uint* D; int c;
  if (r < 256) { S = Wfij + l * 16384; c = r; D = WtF + l * 8192 + r * 32; }
  else {
    int c3 = r - 256; int arr = c3 >> 8; c = c3 & 255;
    S = (arr == 0 ? Wni : arr == 1 ? Wnj : Wnode) + l * 16384;
    D = Wt3 + l * 24576 + c3 * 32;
  }
  for (int k8 = 0; k8 < 8; k8++) {
    uint u0 = packbf(S[(k8*8+0)*256 + c], S[(k8*8+1)*256 + c]);
    uint u1 = packbf(S[(k8*8+2)*256 + c], S[(k8*8+3)*256 + c]);
    uint u2 = packbf(S[(k8*8+4)*256 + c], S[(k8*8+5)*256 + c]);
    uint u3 = packbf(S[(k8*8+6)*256 + c], S[(k8*8+7)*256 + c]);
    *((uint4*)(D + k8 * 4)) = make_uint4(u0, u1, u2, u3);
  }
}

// MFMA node projections: D[c3][n] = sum_k Wt3[c3][k] h[n][k]  (c3 in 768 = ni|nj|node)
__global__ __launch_bounds__(256) void proj_mfma(
    const uint4* __restrict__ h_bf, const uint4* __restrict__ Wt3_l,
    const float* __restrict__ bnd_l,
    uint2* __restrict__ hni, uint2* __restrict__ hnj, uint2* __restrict__ hpj)
{
  int t = threadIdx.x, lane = t & 63, w = t >> 6;
  int col = lane & 15, quad = lane >> 4;
  for (int ch = 0; ch < 2; ch++) {
    int n = blockIdx.x * 32 + ch * 16 + col;
    bf16x8 b0 = *(const bf16x8*)&h_bf[(long)n * 8 + quad];
    bf16x8 b1 = *(const bf16x8*)&h_bf[(long)n * 8 + 4 + quad];
    f32x4 acc[12];
    #pragma unroll
    for (int ct = 0; ct < 12; ct++) acc[ct] = (f32x4){0.f, 0.f, 0.f, 0.f};
    #pragma unroll
    for (int ct = 0; ct < 12; ct++) {
      int cg = w * 192 + ct * 16 + col;
      bf16x8 a0 = *(const bf16x8*)&Wt3_l[(long)cg * 8 + quad];
      bf16x8 a1 = *(const bf16x8*)&Wt3_l[(long)cg * 8 + 4 + quad];
      acc[ct] = __builtin_amdgcn_mfma_f32_16x16x32_bf16(a0, b0, acc[ct], 0, 0, 0);
      acc[ct] = __builtin_amdgcn_mfma_f32_16x16x32_bf16(a1, b1, acc[ct], 0, 0, 0);
    }
    #pragma unroll
    for (int ct = 0; ct < 12; ct++) {
      int cg0 = w * 192 + ct * 16 + quad * 4;
      int arr = cg0 >> 8;
      int c = cg0 & 255;
      float x0 = acc[ct][0], x1 = acc[ct][1], x2 = acc[ct][2], x3 = acc[ct][3];
      if (arr == 2) { float4 bb = ld4(bnd_l + c); x0 += bb.x; x1 += bb.y; x2 += bb.z; x3 += bb.w; }
      uint2* dp = arr == 0 ? hni : arr == 1 ? hnj : hpj;
      dp[(long)n * 64 + (c >> 2)] = make_uint2(packbf(x0, x1), packbf(x2, x3));
    }
  }
}

// MFMA fused edge pass, low-VGPR variant: tiles grouped by within-head index j;
// epilogue consumed incrementally so only 4 acc tiles live at a time.
__global__ __launch_bounds__(256) void edge_mfma(
    const uint4* __restrict__ f_bf, const uint2* __restrict__ hni,
    const uint2* __restrict__ hnj, const uint4* __restrict__ WtF_l,
    const float* __restrict__ be_l, const float* __restrict__ attn_l,
    const int* __restrict__ src, const int* __restrict__ dst,
    float* __restrict__ score, uint2* __restrict__ f_next)
{
  __shared__ uint Wsh[256 * 36];   // rows padded to 72 bf16
  int t = threadIdx.x;
  #pragma unroll
  for (int i = 0; i < 8; i++) {
    int g = t + i * 256;
    int c = g >> 3, pos = g & 7;
    uint4 v = WtF_l[c * 8 + pos];
    *((uint4*)&Wsh[c * 36 + pos * 4]) = v;
  }
  __syncthreads();
  int lane = t & 63, w = t >> 6;
  int col = lane & 15, quad = lane >> 4;
  #pragma unroll 1
  for (int ch = 0; ch < 2; ch++) {
    int e = blockIdx.x * 128 + ch * 64 + w * 16 + col;
    int ee = e < NE ? e : NE - 1;
    int s_ = src[ee], d_ = dst[ee];
    bf16x8 b0 = *(const bf16x8*)&f_bf[(long)ee * 8 + quad];
    bf16x8 b1 = *(const bf16x8*)&f_bf[(long)ee * 8 + 4 + quad];
    const uint2* ni = hni + (long)s_ * 64;
    const uint2* nj = hnj + (long)d_ * 64;
    float m[4][4];
    float sh0 = 0.f, sh1 = 0.f, sh2 = 0.f, sh3 = 0.f;
    float s1 = 0.f, s2 = 0.f;
    #pragma unroll
    for (int j = 0; j < 4; j++) {
      f32x4 acc[4];
      #pragma unroll
      for (int hg = 0; hg < 4; hg++) {
        int c = (hg * 4 + j) * 16 + col;
        bf16x8 a0 = *((const bf16x8*)&Wsh[c * 36 + quad * 4]);
        bf16x8 a1 = *((const bf16x8*)&Wsh[c * 36 + 16 + quad * 4]);
        acc[hg] = (f32x4){0.f, 0.f, 0.f, 0.f};
        acc[hg] = __builtin_amdgcn_mfma_f32_16x16x32_bf16(a0, b0, acc[hg], 0, 0, 0);
        acc[hg] = __builtin_amdgcn_mfma_f32_16x16x32_bf16(a1, b1, acc[hg], 0, 0, 0);
      }
      float m0 = 0.f, m1 = 0.f, m2 = 0.f, m3 = 0.f;
      #pragma unroll
      for (int hg = 0; hg < 4; hg++) {
        int ct = hg * 4 + j;
        int c = ct * 16 + quad * 4;
        float4 a = up4(ni[ct * 4 + quad]);
        float4 b = up4(nj[ct * 4 + quad]);
        float4 bb = ld4(be_l + c);
        float4 at = ld4(attn_l + c);
        float x0 = acc[hg][0] + a.x + b.x + bb.x;
        float x1 = acc[hg][1] + a.y + b.y + bb.y;
        float x2 = acc[hg][2] + a.z + b.z + bb.z;
        float x3 = acc[hg][3] + a.w + b.w + bb.w;
        float l0 = x0 > 0.f ? x0 : 0.01f * x0;
        float l1 = x1 > 0.f ? x1 : 0.01f * x1;
        float l2 = x2 > 0.f ? x2 : 0.01f * x2;
        float l3 = x3 > 0.f ? x3 : 0.01f * x3;
        float dp = l0 * at.x + l1 * at.y + l2 * at.z + l3 * at.w;
        if (hg == 0) sh0 += dp; else if (hg == 1) sh1 += dp;
        else if (hg == 2) sh2 += dp; else sh3 += dp;
        m0 += x0; m1 += x1; m2 += x2; m3 += x3;
      }
      m0 *= 0.25f; m1 *= 0.25f; m2 *= 0.25f; m3 *= 0.25f;
      m[j][0] = m0; m[j][1] = m1; m[j][2] = m2; m[j][3] = m3;
      s1 += m0 + m1 + m2 + m3;
      s2 += m0 * m0 + m1 * m1 + m2 * m2 + m3 * m3;
    }
    sh0 += __shfl_xor(sh0, 16); sh0 += __shfl_xor(sh0, 32);
    sh1 += __shfl_xor(sh1, 16); sh1 += __shfl_xor(sh1, 32);
    sh2 += __shfl_xor(sh2, 16); sh2 += __shfl_xor(sh2, 32);
    sh3 += __shfl_xor(sh3, 16); sh3 += __shfl_xor(sh3, 32);
    float sv = quad == 0 ? sh0 : quad == 1 ? sh1 : quad == 2 ? sh2 : sh3;
    s1 += __shfl_xor(s1, 16); s2 += __shfl_xor(s2, 16);
    s1 += __shfl_xor(s1, 32); s2 += __shfl_xor(s2, 32);
    float mean = s1 * 0.015625f;
    float var  = s2 * 0.015625f - mean * mean;
    float rs = rsqrtf(var + 1e-5f);
    if (e < NE) {
      score[e * 4 + quad] = sv;
      #pragma unroll
      for (int j = 0; j < 4; j++) {
        float o0 = (m[j][0] - mean) * rs; o0 = o0 > 0.f ? o0 : expm1f(o0);
        float o1 = (m[j][1] - mean) * rs; o1 = o1 > 0.f ? o1 : expm1f(o1);
        float o2 = (m[j][2] - mean) * rs; o2 = o2 > 0.f ? o2 : expm1f(o2);
        float o3 = (m[j][3] - mean) * rs; o3 = o3 > 0.f ? o3 : expm1f(o3);
        f_next[(long)e * 16 + j * 4 + quad] = make_uint2(packbf(o0, o1), packbf(o2, o3));
      }
    }
  }
}

// One wave per dst node; half-wave per edge (2 edges/iter), 16B coalesced hproj rows.
// lane = half*32 + seg; seg owns channels seg*8..seg*8+7 (head = seg>>3).
__global__ __launch_bounds__(256) void agg_kernel(
    const uint4* __restrict__ hproj, const float* __restrict__ score,
    const int* __restrict__ src, const int* __restrict__ elist,
    const int* __restrict__ off, uint4* __restrict__ h_next)
{
  int gw = (blockIdx.x * 256 + threadIdx.x) >> 6;
  int lane = threadIdx.x & 63;
  if (gw >= NN) return;
  int half = lane >> 5, seg = lane & 31;
  int hh = seg >> 3;
  int o0 = off[gw], o1 = off[gw + 1];
  if (o0 == o1) {
    if (lane < 8) h_next[(long)gw * 8 + lane] = make_uint4(0u, 0u, 0u, 0u);
    return;
  }
  float mx = -3.0e38f;
  for (int i = o0 + half; i < o1; i += 2)
    mx = fmaxf(mx, score[elist[i] * 4 + hh]);
  mx = fmaxf(mx, __shfl_xor(mx, 32));
  float a0 = 0.f, a1 = 0.f, a2 = 0.f, a3 = 0.f, a4 = 0.f, a5 = 0.f, a6 = 0.f, a7 = 0.f;
  float den = 0.f;
  for (int i = o0 + half; i < o1; i += 2) {
    int e = elist[i];
    float wgt = __expf(score[e * 4 + hh] - mx);
    den += wgt;
    uint4 v = hproj[(long)src[e] * 32 + seg];
    float4 p0 = up4(make_uint2(v.x, v.y));
    float4 p1 = up4(make_uint2(v.z, v.w));
    a0 = fmaf(wgt, p0.x, a0); a1 = fmaf(wgt, p0.y, a1);
    a2 = fmaf(wgt, p0.z, a2); a3 = fmaf(wgt, p0.w, a3);
    a4 = fmaf(wgt, p1.x, a4); a5 = fmaf(wgt, p1.y, a5);
    a6 = fmaf(wgt, p1.z, a6); a7 = fmaf(wgt, p1.w, a7);
  }
  den += __shfl_xor(den, 32);
  a0 += __shfl_xor(a0, 32); a1 += __shfl_xor(a1, 32);
  a2 += __shfl_xor(a2, 32); a3 += __shfl_xor(a3, 32);
  a4 += __shfl_xor(a4, 32); a5 += __shfl_xor(a5, 32);
  a6 += __shfl_xor(a6, 32); a7 += __shfl_xor(a7, 32);
  float inv = 1.f / den;
  float v0 = a0 * inv, v1 = a1 * inv, v2 = a2 * inv, v3 = a3 * inv;
  float v4 = a4 * inv, v5 = a5 * inv, v6 = a6 * inv, v7 = a7 * inv;
  // head fold: sum over lane bits 3,4 (head bits), then /4
  v0 += __shfl_xor(v0, 8); v0 += __shfl_xor(v0, 16); v0 *= 0.25f;
  v1 += __shfl_xor(v1, 8); v1 += __shfl_xor(v1, 16); v1 *= 0.25f;
  v2 += __shfl_xor(v2, 8); v2 += __shfl_xor(v2, 16); v2 *= 0.25f;
  v3 += __shfl_xor(v3, 8); v3 += __shfl_xor(v3, 16); v3 *= 0.25f;
  v4 += __shfl_xor(v4, 8); v4 += __shfl_xor(v4, 16); v4 *= 0.25f;
  v5 += __shfl_xor(v5, 8); v5 += __shfl_xor(v5, 16); v5 *= 0.25f;
  v6 += __shfl_xor(v6, 8); v6 += __shfl_xor(v6, 16); v6 *= 0.25f;
  v7 += __shfl_xor(v7, 8); v7 += __shfl_xor(v7, 16); v7 *= 0.25f;
  float s1 = v0 + v1 + v2 + v3 + v4 + v5 + v6 + v7;
  float s2 = v0*v0 + v1*v1 + v2*v2 + v3*v3 + v4*v4 + v5*v5 + v6*v6 + v7*v7;
  s1 += __shfl_xor(s1, 1); s2 += __shfl_xor(s2, 1);
  s1 += __shfl_xor(s1, 2); s2 += __shfl_xor(s2, 2);
  s1 += __shfl_xor(s1, 4); s2 += __shfl_xor(s2, 4);
  float mean = s1 * 0.015625f;
  float var  = s2 * 0.015625f - mean * mean;
  float rs = rsqrtf(var + 1e-5f);
  if (lane < 8) {
    float o0 = (v0 - mean) * rs; o0 = o0 > 0.f ? o0 : expm1f(o0);
    float o1 = (v1 - mean) * rs; o1 = o1 > 0.f ? o1 : expm1f(o1);
    float o2 = (v2 - mean) * rs; o2 = o2 > 0.f ? o2 : expm1f(o2);
    float o3 = (v3 - mean) * rs; o3 = o3 > 0.f ? o3 : expm1f(o3);
    float o4 = (v4 - mean) * rs; o4 = o4 > 0.f ? o4 : expm1f(o4);
    float o5 = (v5 - mean) * rs; o5 = o5 > 0.f ? o5 : expm1f(o5);
    float o6 = (v6 - mean) * rs; o6 = o6 > 0.f ? o6 : expm1f(o6);
    float o7 = (v7 - mean) * rs; o7 = o7 > 0.f ? o7 : expm1f(o7);
    h_next[(long)gw * 8 + lane] =
        make_uint4(packbf(o0, o1), packbf(o2, o3), packbf(o4, o5), packbf(o6, o7));
  }
}

// out[m][j] = sum_k bf16(h)[m][k] * Wf[k][j] + bf[j]
__global__ void final_gemm(const uint2* __restrict__ h, const float* __restrict__ Wf,
                           const float* __restrict__ bf_, float* __restrict__ out) {
  int idx = blockIdx.x * 256 + threadIdx.x;
  if (idx >= NN * 16) return;
  int m = idx >> 4, j4 = (idx & 15) << 2;
  const uint2* row = h + (long)m * 16;
  float ax = 0.f, ay = 0.f, az = 0.f, aw = 0.f;
  for (int kk = 0; kk < 16; kk++) {
    float4 a = up4(row[kk]);
    float4 b0 = ld4(Wf + (kk * 4 + 0) * 64 + j4);
    float4 b1 = ld4(Wf + (kk * 4 + 1) * 64 + j4);
    float4 b2 = ld4(Wf + (kk * 4 + 2) * 64 + j4);
    float4 b3 = ld4(Wf + (kk * 4 + 3) * 64 + j4);
    ax = fmaf(a.x, b0.x, ax); ay = fmaf(a.x, b0.y, ay); az = fmaf(a.x, b0.z, az); aw = fmaf(a.x, b0.w, aw);
    ax = fmaf(a.y, b1.x, ax); ay = fmaf(a.y, b1.y, ay); az = fmaf(a.y, b1.z, az); aw = fmaf(a.y, b1.w, aw);
    ax = fmaf(a.z, b2.x, ax); ay = fmaf(a.z, b2.y, ay); az = fmaf(a.z, b2.z, az); aw = fmaf(a.z, b2.w, aw);
    ax = fmaf(a.w, b3.x, ax); ay = fmaf(a.w, b3.y, ay); az = fmaf(a.w, b3.z, az); aw = fmaf(a.w, b3.w, aw);
  }
  float4 bb = ld4(bf_ + j4);
  *(float4*)(out + (long)m * 64 + j4) = make_float4(ax + bb.x, ay + bb.y, az + bb.z, aw + bb.w);
}

extern "C" void kernel_launch(void* const* d_in, const int* in_sizes, int n_in,
                              void* d_out, int out_size, void* d_ws, size_t ws_size,
                              hipStream_t stream) {
  const float* x      = (const float*)d_in[0];
  const float* efeat  = (const float*)d_in[1];
  const int*   src    = (const int*)d_in[2];
  const int*   dst    = (const int*)d_in[3];
  const float* Wn0    = (const float*)d_in[4];
  const float* bn0    = (const float*)d_in[5];
  const float* We0    = (const float*)d_in[6];
  const float* be0    = (const float*)d_in[7];
  const float* Wnode  = (const float*)d_in[8];
  const float* bnode  = (const float*)d_in[9];
  const float* Wni    = (const float*)d_in[10];
  const float* Wnj    = (const float*)d_in[11];
  const float* Wfij   = (const float*)d_in[12];
  const float* attn   = (const float*)d_in[13];
  const float* bias_e = (const float*)d_in[14];
  const float* Wf     = (const float*)d_in[15];
  const float* bf     = (const float*)d_in[16];
  float* out = (float*)d_out;

  char* w = (char*)d_ws;
  auto alloc = [&](size_t nbytes) { char* p = w; w += (nbytes + 255) & ~(size_t)255; return p; };
  uint2* h_a  = (uint2*)alloc((size_t)NN * 128);   // bf16 [NN][64]
  uint2* h_b  = (uint2*)alloc((size_t)NN * 128);
  uint2* f_a  = (uint2*)alloc((size_t)NE * 128);   // bf16 [NE][64]
  uint2* f_b  = (uint2*)alloc((size_t)NE * 128);
  uint2* hni  = (uint2*)alloc((size_t)NN * 512);   // bf16 [NN][256]
  uint2* hnj  = (uint2*)alloc((size_t)NN * 512);
  uint2* hpj  = (uint2*)alloc((size_t)NN * 512);
  float* sc   = (float*)alloc((size_t)NE * 16);
  uint*  WtF  = (uint*)alloc((size_t)2 * 8192 * 4);    // [2][256][64] bf16
  uint*  Wt3  = (uint*)alloc((size_t)2 * 24576 * 4);   // [2][768][64] bf16
  int* deg    = (int*)alloc((size_t)NN * 2 * 4);
  int* cursor = deg + NN;
  int* off    = (int*)alloc((size_t)(NN + 1) * 4);
  int* elist  = (int*)alloc((size_t)NE * 4);
  int* bsum   = (int*)alloc((size_t)128 * 4);

  // input projections -> bf16
  gemm4_bf16<<<(NN * 16 + 255) / 256, 256, 0, stream>>>(x, Wn0, bn0, h_a, NN, 65, 64);
  gemm4_bf16<<<(NE * 16 + 255) / 256, 256, 0, stream>>>(efeat, We0, be0, f_a, NE, 15, 64);
  prep_w<<<8, 256, 0, stream>>>(Wfij, Wni, Wnj, Wnode, WtF, Wt3);

  // CSR over dst
  zero_i32<<<(2 * NN + 255) / 256, 256, 0, stream>>>(deg, 2 * NN);
  count_deg<<<(NE + 255) / 256, 256, 0, stream>>>(dst, deg);
  scan1<<<SCAN_BLOCKS, 256, 0, stream>>>(deg, off, bsum);
  scan2<<<1, 128, 0, stream>>>(bsum, off);
  scan3<<<SCAN_BLOCKS, 256, 0, stream>>>(off, bsum);
  fill_csr<<<(NE + 255) / 256, 256, 0, stream>>>(dst, off, cursor, elist);

  uint2* hc = h_a; uint2* hn = h_b;
  uint2* fc = f_a; uint2* fn = f_b;
  for (int l = 0; l < 2; l++) {
    const uint4* Wt3_l = (const uint4*)(Wt3 + (size_t)l * 24576);
    const uint4* WtF_l = (const uint4*)(WtF + (size_t)l * 8192);
    const float* bnd_l = bnode + (size_t)l * 256;
    const float* be_l  = bias_e + (size_t)l * 256;
    const float* at_l  = attn + (size_t)l * 256;
    proj_mfma<<<625, 256, 0, stream>>>((const uint4*)hc, Wt3_l, bnd_l, hni, hnj, hpj);
    edge_mfma<<<(NE + 127) / 128, 256, 0, stream>>>((const uint4*)fc, hni, hnj, WtF_l,
                                                    be_l, at_l, src, dst, sc, fn);
    agg_kernel<<<NN / 4, 256, 0, stream>>>((const uint4*)hpj, sc, src, elist, off,
                                           (uint4*)hn);
    uint2* tmp = hc; hc = hn; hn = tmp;
    tmp = fc; fc = fn; fn = tmp;
  }
  final_gemm<<<(NN * 16 + 255) / 256, 256, 0, stream>>>(hc, Wf, bf, out);
}

// Round 5
// 511.036 us; speedup vs baseline: 2.1258x; 1.1091x over previous
//
#include <hip/hip_runtime.h>
#include <cmath>

#define NN 20000
#define NE 200000
#define SCAN_BLOCKS 79  // ceil(NN/256)

typedef __attribute__((ext_vector_type(8))) short bf16x8;
typedef __attribute__((ext_vector_type(4))) float f32x4;
typedef unsigned int uint;

__device__ __forceinline__ float4 ld4(const float* p){ return *(const float4*)p; }

// RNE float->bf16
__device__ __forceinline__ uint packbf(float a, float b) {
  uint ua = __float_as_uint(a);
  uint ub = __float_as_uint(b);
  ua = (ua + 0x7fffu + ((ua >> 16) & 1u)) >> 16;
  ub = (ub + 0x7fffu + ((ub >> 16) & 1u)) >> 16;
  return ua | (ub << 16);
}
__device__ __forceinline__ float4 up4(uint2 u) {
  return make_float4(__uint_as_float(u.x << 16), __uint_as_float(u.x & 0xffff0000u),
                     __uint_as_float(u.y << 16), __uint_as_float(u.y & 0xffff0000u));
}

// naive GEMM -> packed bf16 out. O[m][j]=sum_k A[m][k]B[k][j]+bias[j]
__global__ void gemm4_bf16(const float* __restrict__ A, const float* __restrict__ B,
                           const float* __restrict__ bias, uint2* __restrict__ O,
                           int M, int K, int Nout) {
  int jt = Nout >> 2;
  int idx = blockIdx.x * 256 + threadIdx.x;
  if (idx >= M * jt) return;
  int m = idx / jt;
  int j4 = (idx - m * jt) << 2;
  const float* a = A + (long)m * K;
  const float* b = B + j4;
  float ax = 0.f, ay = 0.f, az = 0.f, aw = 0.f;
  for (int k = 0; k < K; k++) {
    float av = a[k];
    float4 bv = ld4(b + (long)k * Nout);
    ax = fmaf(av, bv.x, ax); ay = fmaf(av, bv.y, ay);
    az = fmaf(av, bv.z, az); aw = fmaf(av, bv.w, aw);
  }
  if (bias) { float4 bb = ld4(bias + j4); ax += bb.x; ay += bb.y; az += bb.z; aw += bb.w; }
  O[(long)m * jt + (j4 >> 2)] = make_uint2(packbf(ax, ay), packbf(az, aw));
}

__global__ void zero_i32(int* __restrict__ p, int n) {
  int i = blockIdx.x * 256 + threadIdx.x;
  if (i < n) p[i] = 0;
}

__global__ void count_deg(const int* __restrict__ dst, int* __restrict__ deg) {
  int e = blockIdx.x * 256 + threadIdx.x;
  if (e < NE) atomicAdd(&deg[dst[e]], 1);
}

__global__ void scan1(const int* __restrict__ deg, int* __restrict__ off, int* __restrict__ bsum) {
  __shared__ int buf[256];
  int t = threadIdx.x;
  int g = blockIdx.x * 256 + t;
  int v = (g < NN) ? deg[g] : 0;
  buf[t] = v;
  __syncthreads();
  for (int s = 1; s < 256; s <<= 1) {
    int x = (t >= s) ? buf[t - s] : 0;
    __syncthreads();
    buf[t] += x;
    __syncthreads();
  }
  if (g < NN) off[g] = buf[t] - v;
  if (t == 255) bsum[blockIdx.x] = buf[255];
}

__global__ void scan2(int* __restrict__ bsum, int* __restrict__ off) {
  __shared__ int buf[128];
  int t = threadIdx.x;
  int v = (t < SCAN_BLOCKS) ? bsum[t] : 0;
  buf[t] = v;
  __syncthreads();
  for (int s = 1; s < 128; s <<= 1) {
    int x = (t >= s) ? buf[t - s] : 0;
    __syncthreads();
    buf[t] += x;
    __syncthreads();
  }
  if (t < SCAN_BLOCKS) bsum[t] = buf[t] - v;
  if (t == 127) off[NN] = buf[127];
}

__global__ void scan3(int* __restrict__ off, const int* __restrict__ bsum) {
  int g = blockIdx.x * 256 + threadIdx.x;
  if (g < NN) off[g] += bsum[blockIdx.x];
}

__global__ void fill_csr(const int* __restrict__ dst, const int* __restrict__ off,
                         int* __restrict__ cursor, int* __restrict__ elist) {
  int e = blockIdx.x * 256 + threadIdx.x;
  if (e >= NE) return;
  int d = dst[e];
  int p = atomicAdd(&cursor[d], 1);
  elist[off[d] + p] = e;
}

// Build Wcat[l][c][k] bf16, k in [0,192) = concat(Wni[:,c], Wnj[:,c], Wfij[:,c]);
// and Wtn[l][c][k] bf16, k in [0,64) = Wnode[:,c]. One thread per row.
__global__ void prep_w(const float* __restrict__ Wni, const float* __restrict__ Wnj,
                       const float* __restrict__ Wfij, const float* __restrict__ Wnode,
                       uint* __restrict__ Wcat, uint* __restrict__ Wtn) {
  int rid = blockIdx.x * 256 + threadIdx.x;
  if (rid >= 1024) return;
  int l = rid >> 9, r = rid & 511;
  if (r < 256) {
    int c = r;
    uint* D = Wcat + (size_t)l * 24576 + c * 96;
    for (int k8 = 0; k8 < 24; k8++) {
      int ss = k8 >> 3;
      const float* S = (ss == 0 ? Wni : ss == 1 ? Wnj : Wfij) + l * 16384;
      int kl = (k8 & 7) * 8;
      uint u0 = packbf(S[(kl+0)*256 + c], S[(kl+1)*256 + c]);
      uint u1 = packbf(S[(kl+2)*256 + c], S[(kl+3)*256 + c]);
      uint u2 = packbf(S[(kl+4)*256 + c], S[(kl+5)*256 + c]);
      uint u3 = packbf(S[(kl+6)*256 + c], S[(kl+7)*256 + c]);
      *((uint4*)(D + k8 * 4)) = make_uint4(u0, u1, u2, u3);
    }
  } else {
    int c = r - 256;
    const float* S = Wnode + l * 16384;
    uint* D = Wtn + (size_t)l * 8192 + c * 32;
    for (int k8 = 0; k8 < 8; k8++) {
      int kl = k8 * 8;
      uint u0 = packbf(S[(kl+0)*256 + c], S[(kl+1)*256 + c]);
      uint u1 = packbf(S[(kl+2)*256 + c], S[(kl+3)*256 + c]);
      uint u2 = packbf(S[(kl+4)*256 + c], S[(kl+5)*256 + c]);
      uint u3 = packbf(S[(kl+6)*256 + c], S[(kl+7)*256 + c]);
      *((uint4*)(D + k8 * 4)) = make_uint4(u0, u1, u2, u3);
    }
  }
}

// Node projection (Wnode only): hpj[n][c] = sum_k h[n][k] Wnode[k][c] + bnode[c]
// wave w owns channels [w*64, w*64+64); 32 nodes per block.
__global__ __launch_bounds__(256) void proj_mfma(
    const uint4* __restrict__ h_bf, const uint* __restrict__ Wtn_l,
    const float* __restrict__ bnd_l, uint2* __restrict__ hpj)
{
  int t = threadIdx.x, lane = t & 63, w = t >> 6;
  int col = lane & 15, quad = lane >> 4;
  bf16x8 A[4][2];
  #pragma unroll
  for (int tt = 0; tt < 4; tt++) {
    int c = (w * 4 + tt) * 16 + col;
    A[tt][0] = *(const bf16x8*)&Wtn_l[c * 32 + quad * 4];
    A[tt][1] = *(const bf16x8*)&Wtn_l[c * 32 + 16 + quad * 4];
  }
  for (int ch = 0; ch < 2; ch++) {
    int n = blockIdx.x * 32 + ch * 16 + col;
    bf16x8 b0 = *(const bf16x8*)&h_bf[(long)n * 8 + quad];
    bf16x8 b1 = *(const bf16x8*)&h_bf[(long)n * 8 + 4 + quad];
    #pragma unroll
    for (int tt = 0; tt < 4; tt++) {
      f32x4 acc = (f32x4){0.f, 0.f, 0.f, 0.f};
      acc = __builtin_amdgcn_mfma_f32_16x16x32_bf16(A[tt][0], b0, acc, 0, 0, 0);
      acc = __builtin_amdgcn_mfma_f32_16x16x32_bf16(A[tt][1], b1, acc, 0, 0, 0);
      int c = (w * 4 + tt) * 16 + quad * 4;
      float4 bb = ld4(bnd_l + c);
      hpj[(long)n * 64 + (c >> 2)] =
          make_uint2(packbf(acc[0] + bb.x, acc[1] + bb.y), packbf(acc[2] + bb.z, acc[3] + bb.w));
    }
  }
}

// Fused edge pass, K=192: f_out = h[src]@Wni + h[dst]@Wnj + f@Wfij + bias.
// Gathers only 64-ch h rows (2.5 MB table, L2-resident). Wave w owns within-head
// index j=w (tiles ct=4*hg+w); A-frags live in registers; cross-wave stats via LDS.
__global__ __launch_bounds__(256) void edge_mfma(
    const uint4* __restrict__ f_bf, const uint4* __restrict__ h_bf,
    const uint* __restrict__ Wcat_l, const float* __restrict__ be_l,
    const float* __restrict__ attn_l, const int* __restrict__ src,
    const int* __restrict__ dst, float* __restrict__ score,
    uint2* __restrict__ f_next)
{
  __shared__ float red[4][16][6];
  int t = threadIdx.x, lane = t & 63, w = t >> 6;
  int col = lane & 15, quad = lane >> 4;
  bf16x8 A[4][6];
  float4 be4[4], at4[4];
  #pragma unroll
  for (int hg = 0; hg < 4; hg++) {
    int c = (4 * hg + w) * 16 + col;
    #pragma unroll
    for (int kt = 0; kt < 6; kt++)
      A[hg][kt] = *(const bf16x8*)&Wcat_l[c * 96 + kt * 16 + quad * 4];
    int ce = (4 * hg + w) * 16 + quad * 4;
    be4[hg] = ld4(be_l + ce);
    at4[hg] = ld4(attn_l + ce);
  }
  #pragma unroll 1
  for (int ch = 0; ch < 8; ch++) {
    int e = blockIdx.x * 128 + ch * 16 + col;
    int ee = e < NE ? e : NE - 1;
    int s_ = src[ee], d_ = dst[ee];
    bf16x8 B[6];
    B[0] = *(const bf16x8*)&h_bf[(long)s_ * 8 + quad];
    B[1] = *(const bf16x8*)&h_bf[(long)s_ * 8 + 4 + quad];
    B[2] = *(const bf16x8*)&h_bf[(long)d_ * 8 + quad];
    B[3] = *(const bf16x8*)&h_bf[(long)d_ * 8 + 4 + quad];
    B[4] = *(const bf16x8*)&f_bf[(long)ee * 8 + quad];
    B[5] = *(const bf16x8*)&f_bf[(long)ee * 8 + 4 + quad];
    float m0 = 0.f, m1 = 0.f, m2 = 0.f, m3 = 0.f;
    float sh0 = 0.f, sh1 = 0.f, sh2 = 0.f, sh3 = 0.f;
    #pragma unroll
    for (int hg = 0; hg < 4; hg++) {
      f32x4 acc = (f32x4){0.f, 0.f, 0.f, 0.f};
      #pragma unroll
      for (int kt = 0; kt < 6; kt++)
        acc = __builtin_amdgcn_mfma_f32_16x16x32_bf16(A[hg][kt], B[kt], acc, 0, 0, 0);
      float x0 = acc[0] + be4[hg].x;
      float x1 = acc[1] + be4[hg].y;
      float x2 = acc[2] + be4[hg].z;
      float x3 = acc[3] + be4[hg].w;
      float l0 = x0 > 0.f ? x0 : 0.01f * x0;
      float l1 = x1 > 0.f ? x1 : 0.01f * x1;
      float l2 = x2 > 0.f ? x2 : 0.01f * x2;
      float l3 = x3 > 0.f ? x3 : 0.01f * x3;
      float dp = l0 * at4[hg].x + l1 * at4[hg].y + l2 * at4[hg].z + l3 * at4[hg].w;
      if (hg == 0) sh0 = dp; else if (hg == 1) sh1 = dp;
      else if (hg == 2) sh2 = dp; else sh3 = dp;
      m0 += x0; m1 += x1; m2 += x2; m3 += x3;
    }
    m0 *= 0.25f; m1 *= 0.25f; m2 *= 0.25f; m3 *= 0.25f;
    float s1 = m0 + m1 + m2 + m3;
    float s2 = m0 * m0 + m1 * m1 + m2 * m2 + m3 * m3;
    sh0 += __shfl_xor(sh0, 16); sh0 += __shfl_xor(sh0, 32);
    sh1 += __shfl_xor(sh1, 16); sh1 += __shfl_xor(sh1, 32);
    sh2 += __shfl_xor(sh2, 16); sh2 += __shfl_xor(sh2, 32);
    sh3 += __shfl_xor(sh3, 16); sh3 += __shfl_xor(sh3, 32);
    s1 += __shfl_xor(s1, 16); s1 += __shfl_xor(s1, 32);
    s2 += __shfl_xor(s2, 16); s2 += __shfl_xor(s2, 32);
    if (quad == 0) {
      red[w][col][0] = sh0; red[w][col][1] = sh1;
      red[w][col][2] = sh2; red[w][col][3] = sh3;
      red[w][col][4] = s1;  red[w][col][5] = s2;
    }
    __syncthreads();
    float svT = red[0][col][quad] + red[1][col][quad] + red[2][col][quad] + red[3][col][quad];
    float s1T = red[0][col][4] + red[1][col][4] + red[2][col][4] + red[3][col][4];
    float s2T = red[0][col][5] + red[1][col][5] + red[2][col][5] + red[3][col][5];
    __syncthreads();
    float mean = s1T * 0.015625f;
    float var  = s2T * 0.015625f - mean * mean;
    float rs = rsqrtf(var + 1e-5f);
    if (e < NE) {
      if (w == 0) score[e * 4 + quad] = svT;
      float o0 = (m0 - mean) * rs; o0 = o0 > 0.f ? o0 : expm1f(o0);
      float o1 = (m1 - mean) * rs; o1 = o1 > 0.f ? o1 : expm1f(o1);
      float o2 = (m2 - mean) * rs; o2 = o2 > 0.f ? o2 : expm1f(o2);
      float o3 = (m3 - mean) * rs; o3 = o3 > 0.f ? o3 : expm1f(o3);
      f_next[(long)e * 16 + w * 4 + quad] = make_uint2(packbf(o0, o1), packbf(o2, o3));
    }
  }
}

// One wave per dst node; half-wave per edge (2 edges/iter), 16B coalesced hproj rows.
__global__ __launch_bounds__(256) void agg_kernel(
    const uint4* __restrict__ hproj, const float* __restrict__ score,
    const int* __restrict__ src, const int* __restrict__ elist,
    const int* __restrict__ off, uint4* __restrict__ h_next)
{
  int gw = (blockIdx.x * 256 + threadIdx.x) >> 6;
  int lane = threadIdx.x & 63;
  if (gw >= NN) return;
  int half = lane >> 5, seg = lane & 31;
  int hh = seg >> 3;
  int o0 = off[gw], o1 = off[gw + 1];
  if (o0 == o1) {
    if (lane < 8) h_next[(long)gw * 8 + lane] = make_uint4(0u, 0u, 0u, 0u);
    return;
  }
  float mx = -3.0e38f;
  for (int i = o0 + half; i < o1; i += 2)
    mx = fmaxf(mx, score[elist[i] * 4 + hh]);
  mx = fmaxf(mx, __shfl_xor(mx, 32));
  float a0 = 0.f, a1 = 0.f, a2 = 0.f, a3 = 0.f, a4 = 0.f, a5 = 0.f, a6 = 0.f, a7 = 0.f;
  float den = 0.f;
  for (int i = o0 + half; i < o1; i += 2) {
    int e = elist[i];
    float wgt = __expf(score[e * 4 + hh] - mx);
    den += wgt;
    uint4 v = hproj[(long)src[e] * 32 + seg];
    float4 p0 = up4(make_uint2(v.x, v.y));
    float4 p1 = up4(make_uint2(v.z, v.w));
    a0 = fmaf(wgt, p0.x, a0); a1 = fmaf(wgt, p0.y, a1);
    a2 = fmaf(wgt, p0.z, a2); a3 = fmaf(wgt, p0.w, a3);
    a4 = fmaf(wgt, p1.x, a4); a5 = fmaf(wgt, p1.y, a5);
    a6 = fmaf(wgt, p1.z, a6); a7 = fmaf(wgt, p1.w, a7);
  }
  den += __shfl_xor(den, 32);
  a0 += __shfl_xor(a0, 32); a1 += __shfl_xor(a1, 32);
  a2 += __shfl_xor(a2, 32); a3 += __shfl_xor(a3, 32);
  a4 += __shfl_xor(a4, 32); a5 += __shfl_xor(a5, 32);
  a6 += __shfl_xor(a6, 32); a7 += __shfl_xor(a7, 32);
  float inv = 1.f / den;
  float v0 = a0 * inv, v1 = a1 * inv, v2 = a2 * inv, v3 = a3 * inv;
  float v4 = a4 * inv, v5 = a5 * inv, v6 = a6 * inv, v7 = a7 * inv;
  v0 += __shfl_xor(v0, 8); v0 += __shfl_xor(v0, 16); v0 *= 0.25f;
  v1 += __shfl_xor(v1, 8); v1 += __shfl_xor(v1, 16); v1 *= 0.25f;
  v2 += __shfl_xor(v2, 8); v2 += __shfl_xor(v2, 16); v2 *= 0.25f;
  v3 += __shfl_xor(v3, 8); v3 += __shfl_xor(v3, 16); v3 *= 0.25f;
  v4 += __shfl_xor(v4, 8); v4 += __shfl_xor(v4, 16); v4 *= 0.25f;
  v5 += __shfl_xor(v5, 8); v5 += __shfl_xor(v5, 16); v5 *= 0.25f;
  v6 += __shfl_xor(v6, 8); v6 += __shfl_xor(v6, 16); v6 *= 0.25f;
  v7 += __shfl_xor(v7, 8); v7 += __shfl_xor(v7, 16); v7 *= 0.25f;
  float s1 = v0 + v1 + v2 + v3 + v4 + v5 + v6 + v7;
  float s2 = v0*v0 + v1*v1 + v2*v2 + v3*v3 + v4*v4 + v5*v5 + v6*v6 + v7*v7;
  s1 += __shfl_xor(s1, 1); s2 += __shfl_xor(s2, 1);
  s1 += __shfl_xor(s1, 2); s2 += __shfl_xor(s2, 2);
  s1 += __shfl_xor(s1, 4); s2 += __shfl_xor(s2, 4);
  float mean = s1 * 0.015625f;
  float var  = s2 * 0.015625f - mean * mean;
  float rs = rsqrtf(var + 1e-5f);
  if (lane < 8) {
    float o0 = (v0 - mean) * rs; o0 = o0 > 0.f ? o0 : expm1f(o0);
    float o1 = (v1 - mean) * rs; o1 = o1 > 0.f ? o1 : expm1f(o1);
    float o2 = (v2 - mean) * rs; o2 = o2 > 0.f ? o2 : expm1f(o2);
    float o3 = (v3 - mean) * rs; o3 = o3 > 0.f ? o3 : expm1f(o3);
    float o4 = (v4 - mean) * rs; o4 = o4 > 0.f ? o4 : expm1f(o4);
    float o5 = (v5 - mean) * rs; o5 = o5 > 0.f ? o5 : expm1f(o5);
    float o6 = (v6 - mean) * rs; o6 = o6 > 0.f ? o6 : expm1f(o6);
    float o7 = (v7 - mean) * rs; o7 = o7 > 0.f ? o7 : expm1f(o7);
    h_next[(long)gw * 8 + lane] =
        make_uint4(packbf(o0, o1), packbf(o2, o3), packbf(o4, o5), packbf(o6, o7));
  }
}

// out[m][j] = sum_k bf16(h)[m][k] * Wf[k][j] + bf[j]
__global__ void final_gemm(const uint2* __restrict__ h, const float* __restrict__ Wf,
                           const float* __restrict__ bf_, float* __restrict__ out) {
  int idx = blockIdx.x * 256 + threadIdx.x;
  if (idx >= NN * 16) return;
  int m = idx >> 4, j4 = (idx & 15) << 2;
  const uint2* row = h + (long)m * 16;
  float ax = 0.f, ay = 0.f, az = 0.f, aw = 0.f;
  for (int kk = 0; kk < 16; kk++) {
    float4 a = up4(row[kk]);
    float4 b0 = ld4(Wf + (kk * 4 + 0) * 64 + j4);
    float4 b1 = ld4(Wf + (kk * 4 + 1) * 64 + j4);
    float4 b2 = ld4(Wf + (kk * 4 + 2) * 64 + j4);
    float4 b3 = ld4(Wf + (kk * 4 + 3) * 64 + j4);
    ax = fmaf(a.x, b0.x, ax); ay = fmaf(a.x, b0.y, ay); az = fmaf(a.x, b0.z, az); aw = fmaf(a.x, b0.w, aw);
    ax = fmaf(a.y, b1.x, ax); ay = fmaf(a.y, b1.y, ay); az = fmaf(a.y, b1.z, az); aw = fmaf(a.y, b1.w, aw);
    ax = fmaf(a.z, b2.x, ax); ay = fmaf(a.z, b2.y, ay); az = fmaf(a.z, b2.z, az); aw = fmaf(a.z, b2.w, aw);
    ax = fmaf(a.w, b3.x, ax); ay = fmaf(a.w, b3.y, ay); az = fmaf(a.w, b3.z, az); aw = fmaf(a.w, b3.w, aw);
  }
  float4 bb = ld4(bf_ + j4);
  *(float4*)(out + (long)m * 64 + j4) = make_float4(ax + bb.x, ay + bb.y, az + bb.z, aw + bb.w);
}

extern "C" void kernel_launch(void* const* d_in, const int* in_sizes, int n_in,
                              void* d_out, int out_size, void* d_ws, size_t ws_size,
                              hipStream_t stream) {
  const float* x      = (const float*)d_in[0];
  const float* efeat  = (const float*)d_in[1];
  const int*   src    = (const int*)d_in[2];
  const int*   dst    = (const int*)d_in[3];
  const float* Wn0    = (const float*)d_in[4];
  const float* bn0    = (const float*)d_in[5];
  const float* We0    = (const float*)d_in[6];
  const float* be0    = (const float*)d_in[7];
  const float* Wnode  = (const float*)d_in[8];
  const float* bnode  = (const float*)d_in[9];
  const float* Wni    = (const float*)d_in[10];
  const float* Wnj    = (const float*)d_in[11];
  const float* Wfij   = (const float*)d_in[12];
  const float* attn   = (const float*)d_in[13];
  const float* bias_e = (const float*)d_in[14];
  const float* Wf     = (const float*)d_in[15];
  const float* bf     = (const float*)d_in[16];
  float* out = (float*)d_out;

  char* w = (char*)d_ws;
  auto alloc = [&](size_t nbytes) { char* p = w; w += (nbytes + 255) & ~(size_t)255; return p; };
  uint2* h_a  = (uint2*)alloc((size_t)NN * 128);   // bf16 [NN][64]
  uint2* h_b  = (uint2*)alloc((size_t)NN * 128);
  uint2* f_a  = (uint2*)alloc((size_t)NE * 128);   // bf16 [NE][64]
  uint2* f_b  = (uint2*)alloc((size_t)NE * 128);
  uint2* hpj  = (uint2*)alloc((size_t)NN * 512);   // bf16 [NN][256]
  float* sc   = (float*)alloc((size_t)NE * 16);
  uint*  Wcat = (uint*)alloc((size_t)2 * 24576 * 4);  // [2][256][192] bf16
  uint*  Wtn  = (uint*)alloc((size_t)2 * 8192 * 4);   // [2][256][64] bf16
  int* deg    = (int*)alloc((size_t)NN * 2 * 4);
  int* cursor = deg + NN;
  int* off    = (int*)alloc((size_t)(NN + 1) * 4);
  int* elist  = (int*)alloc((size_t)NE * 4);
  int* bsum   = (int*)alloc((size_t)128 * 4);

  // input projections -> bf16
  gemm4_bf16<<<(NN * 16 + 255) / 256, 256, 0, stream>>>(x, Wn0, bn0, h_a, NN, 65, 64);
  gemm4_bf16<<<(NE * 16 + 255) / 256, 256, 0, stream>>>(efeat, We0, be0, f_a, NE, 15, 64);
  prep_w<<<4, 256, 0, stream>>>(Wni, Wnj, Wfij, Wnode, Wcat, Wtn);

  // CSR over dst
  zero_i32<<<(2 * NN + 255) / 256, 256, 0, stream>>>(deg, 2 * NN);
  count_deg<<<(NE + 255) / 256, 256, 0, stream>>>(dst, deg);
  scan1<<<SCAN_BLOCKS, 256, 0, stream>>>(deg, off, bsum);
  scan2<<<1, 128, 0, stream>>>(bsum, off);
  scan3<<<SCAN_BLOCKS, 256, 0, stream>>>(off, bsum);
  fill_csr<<<(NE + 255) / 256, 256, 0, stream>>>(dst, off, cursor, elist);

  uint2* hc = h_a; uint2* hn = h_b;
  uint2* fc = f_a; uint2* fn = f_b;
  for (int l = 0; l < 2; l++) {
    const uint* Wcat_l = Wcat + (size_t)l * 24576;
    const uint* Wtn_l  = Wtn + (size_t)l * 8192;
    const float* bnd_l = bnode + (size_t)l * 256;
    const float* be_l  = bias_e + (size_t)l * 256;
    const float* at_l  = attn + (size_t)l * 256;
    proj_mfma<<<625, 256, 0, stream>>>((const uint4*)hc, Wtn_l, bnd_l, hpj);
    edge_mfma<<<(NE + 127) / 128, 256, 0, stream>>>((const uint4*)fc, (const uint4*)hc,
                                                    Wcat_l, be_l, at_l, src, dst, sc, fn);
    agg_kernel<<<NN / 4, 256, 0, stream>>>((const uint4*)hpj, sc, src, elist, off,
                                           (uint4*)hn);
    uint2* tmp = hc; hc = hn; hn = tmp;
    tmp = fc; fc = fn; fn = tmp;
  }
  final_gemm<<<(NN * 16 + 255) / 256, 256, 0, stream>>>(hc, Wf, bf, out);
}

// Round 6
// 500.155 us; speedup vs baseline: 2.1720x; 1.0218x over previous
//
#include <hip/hip_runtime.h>
#include <cmath>

#define NN 20000
#define NE 200000
#define SCAN_BLOCKS 79  // ceil(NN/256)

typedef __attribute__((ext_vector_type(8))) short bf16x8;
typedef __attribute__((ext_vector_type(4))) float f32x4;
typedef unsigned int uint;

__device__ __forceinline__ float4 ld4(const float* p){ return *(const float4*)p; }

// RNE float->bf16
__device__ __forceinline__ uint packbf(float a, float b) {
  uint ua = __float_as_uint(a);
  uint ub = __float_as_uint(b);
  ua = (ua + 0x7fffu + ((ua >> 16) & 1u)) >> 16;
  ub = (ub + 0x7fffu + ((ub >> 16) & 1u)) >> 16;
  return ua | (ub << 16);
}
__device__ __forceinline__ float4 up4(uint2 u) {
  return make_float4(__uint_as_float(u.x << 16), __uint_as_float(u.x & 0xffff0000u),
                     __uint_as_float(u.y << 16), __uint_as_float(u.y & 0xffff0000u));
}

// naive GEMM -> packed bf16 out. O[m][j]=sum_k A[m][k]B[k][j]+bias[j]
__global__ void gemm4_bf16(const float* __restrict__ A, const float* __restrict__ B,
                           const float* __restrict__ bias, uint2* __restrict__ O,
                           int M, int K, int Nout) {
  int jt = Nout >> 2;
  int idx = blockIdx.x * 256 + threadIdx.x;
  if (idx >= M * jt) return;
  int m = idx / jt;
  int j4 = (idx - m * jt) << 2;
  const float* a = A + (long)m * K;
  const float* b = B + j4;
  float ax = 0.f, ay = 0.f, az = 0.f, aw = 0.f;
  for (int k = 0; k < K; k++) {
    float av = a[k];
    float4 bv = ld4(b + (long)k * Nout);
    ax = fmaf(av, bv.x, ax); ay = fmaf(av, bv.y, ay);
    az = fmaf(av, bv.z, az); aw = fmaf(av, bv.w, aw);
  }
  if (bias) { float4 bb = ld4(bias + j4); ax += bb.x; ay += bb.y; az += bb.z; aw += bb.w; }
  O[(long)m * jt + (j4 >> 2)] = make_uint2(packbf(ax, ay), packbf(az, aw));
}

__global__ void zero_i32(int* __restrict__ p, int n) {
  int i = blockIdx.x * 256 + threadIdx.x;
  if (i < n) p[i] = 0;
}

__global__ void count_deg(const int* __restrict__ dst, int* __restrict__ deg) {
  int e = blockIdx.x * 256 + threadIdx.x;
  if (e < NE) atomicAdd(&deg[dst[e]], 1);
}

__global__ void scan1(const int* __restrict__ deg, int* __restrict__ off, int* __restrict__ bsum) {
  __shared__ int buf[256];
  int t = threadIdx.x;
  int g = blockIdx.x * 256 + t;
  int v = (g < NN) ? deg[g] : 0;
  buf[t] = v;
  __syncthreads();
  for (int s = 1; s < 256; s <<= 1) {
    int x = (t >= s) ? buf[t - s] : 0;
    __syncthreads();
    buf[t] += x;
    __syncthreads();
  }
  if (g < NN) off[g] = buf[t] - v;
  if (t == 255) bsum[blockIdx.x] = buf[255];
}

__global__ void scan2(int* __restrict__ bsum, int* __restrict__ off) {
  __shared__ int buf[128];
  int t = threadIdx.x;
  int v = (t < SCAN_BLOCKS) ? bsum[t] : 0;
  buf[t] = v;
  __syncthreads();
  for (int s = 1; s < 128; s <<= 1) {
    int x = (t >= s) ? buf[t - s] : 0;
    __syncthreads();
    buf[t] += x;
    __syncthreads();
  }
  if (t < SCAN_BLOCKS) bsum[t] = buf[t] - v;
  if (t == 127) off[NN] = buf[127];
}

__global__ void scan3(int* __restrict__ off, const int* __restrict__ bsum) {
  int g = blockIdx.x * 256 + threadIdx.x;
  if (g < NN) off[g] += bsum[blockIdx.x];
}

// also emits esrc (src in CSR order) and csr_pos (edge -> CSR slot)
__global__ void fill_csr(const int* __restrict__ dst, const int* __restrict__ src,
                         const int* __restrict__ off, int* __restrict__ cursor,
                         int* __restrict__ esrc, int* __restrict__ csr_pos) {
  int e = blockIdx.x * 256 + threadIdx.x;
  if (e >= NE) return;
  int d = dst[e];
  int p = atomicAdd(&cursor[d], 1);
  int pos = off[d] + p;
  esrc[pos] = src[e];
  csr_pos[e] = pos;
}

// Wcat[l][c][k] bf16 (k<192 = Wni|Wnj|Wfij cols), WcT[l][c<64][k<256] = Wnode[kk][h*64+c]/4,
// bmean[l][c<64] = mean_h bnode.
__global__ void prep_w(const float* __restrict__ Wni, const float* __restrict__ Wnj,
                       const float* __restrict__ Wfij, const float* __restrict__ Wnode,
                       const float* __restrict__ bnode,
                       uint* __restrict__ Wcat, uint* __restrict__ WcT,
                       float* __restrict__ bmean) {
  int rid = blockIdx.x * 256 + threadIdx.x;
  if (rid < 512) {
    int l = rid >> 8, c = rid & 255;
    uint* D = Wcat + (size_t)l * 24576 + c * 96;
    for (int k8 = 0; k8 < 24; k8++) {
      int ss = k8 >> 3;
      const float* S = (ss == 0 ? Wni : ss == 1 ? Wnj : Wfij) + l * 16384;
      int kl = (k8 & 7) * 8;
      uint u0 = packbf(S[(kl+0)*256 + c], S[(kl+1)*256 + c]);
      uint u1 = packbf(S[(kl+2)*256 + c], S[(kl+3)*256 + c]);
      uint u2 = packbf(S[(kl+4)*256 + c], S[(kl+5)*256 + c]);
      uint u3 = packbf(S[(kl+6)*256 + c], S[(kl+7)*256 + c]);
      *((uint4*)(D + k8 * 4)) = make_uint4(u0, u1, u2, u3);
    }
  } else if (rid < 640) {
    int idx = rid - 512;
    int l = idx >> 6, c = idx & 63;
    const float* S = Wnode + l * 16384;
    uint* D = WcT + (size_t)l * 8192 + c * 128;
    for (int kp = 0; kp < 128; kp++) {   // uint kp covers k=2kp,2kp+1
      int k0 = kp * 2, k1 = kp * 2 + 1;
      float v0 = S[(k0 & 63) * 256 + (k0 >> 6) * 64 + c] * 0.25f;
      float v1 = S[(k1 & 63) * 256 + (k1 >> 6) * 64 + c] * 0.25f;
      D[kp] = packbf(v0, v1);
    }
  } else if (rid < 768) {
    int idx = rid - 640;
    int l = idx >> 6, c = idx & 63;
    const float* S = bnode + l * 256;
    bmean[l * 64 + c] = 0.25f * (S[c] + S[64 + c] + S[128 + c] + S[192 + c]);
  }
}

// Barrier-free fused edge pass. K=192 MFMA; wave w owns within-head index j=w.
// Writes UNNORMALIZED head-mean partials (f_mid) + per-wave score partials (sc_part).
__global__ __launch_bounds__(256) void edge_mfma(
    const uint4* __restrict__ f_bf, const uint4* __restrict__ h_bf,
    const uint* __restrict__ Wcat_l, const float* __restrict__ be_l,
    const float* __restrict__ attn_l, const int* __restrict__ src,
    const int* __restrict__ dst, float* __restrict__ sc_part,
    uint2* __restrict__ f_mid)
{
  int t = threadIdx.x, lane = t & 63, w = t >> 6;
  int col = lane & 15, quad = lane >> 4;
  bf16x8 A[4][6];
  float4 be4[4], at4[4];
  #pragma unroll
  for (int hg = 0; hg < 4; hg++) {
    int c = (4 * hg + w) * 16 + col;
    #pragma unroll
    for (int kt = 0; kt < 6; kt++)
      A[hg][kt] = *(const bf16x8*)&Wcat_l[c * 96 + kt * 16 + quad * 4];
    int ce = (4 * hg + w) * 16 + quad * 4;
    be4[hg] = ld4(be_l + ce);
    at4[hg] = ld4(attn_l + ce);
  }
  #pragma unroll 1
  for (int ch = 0; ch < 4; ch++) {
    int e = blockIdx.x * 64 + ch * 16 + col;
    int s_ = src[e], d_ = dst[e];
    bf16x8 B[6];
    B[0] = *(const bf16x8*)&h_bf[(long)s_ * 8 + quad];
    B[1] = *(const bf16x8*)&h_bf[(long)s_ * 8 + 4 + quad];
    B[2] = *(const bf16x8*)&h_bf[(long)d_ * 8 + quad];
    B[3] = *(const bf16x8*)&h_bf[(long)d_ * 8 + 4 + quad];
    B[4] = *(const bf16x8*)&f_bf[(long)e * 8 + quad];
    B[5] = *(const bf16x8*)&f_bf[(long)e * 8 + 4 + quad];
    float m0 = 0.f, m1 = 0.f, m2 = 0.f, m3 = 0.f;
    float sh0 = 0.f, sh1 = 0.f, sh2 = 0.f, sh3 = 0.f;
    #pragma unroll
    for (int hg = 0; hg < 4; hg++) {
      f32x4 acc = (f32x4){0.f, 0.f, 0.f, 0.f};
      #pragma unroll
      for (int kt = 0; kt < 6; kt++)
        acc = __builtin_amdgcn_mfma_f32_16x16x32_bf16(A[hg][kt], B[kt], acc, 0, 0, 0);
      float x0 = acc[0] + be4[hg].x;
      float x1 = acc[1] + be4[hg].y;
      float x2 = acc[2] + be4[hg].z;
      float x3 = acc[3] + be4[hg].w;
      float l0 = x0 > 0.f ? x0 : 0.01f * x0;
      float l1 = x1 > 0.f ? x1 : 0.01f * x1;
      float l2 = x2 > 0.f ? x2 : 0.01f * x2;
      float l3 = x3 > 0.f ? x3 : 0.01f * x3;
      float dp = l0 * at4[hg].x + l1 * at4[hg].y + l2 * at4[hg].z + l3 * at4[hg].w;
      if (hg == 0) sh0 = dp; else if (hg == 1) sh1 = dp;
      else if (hg == 2) sh2 = dp; else sh3 = dp;
      m0 += x0; m1 += x1; m2 += x2; m3 += x3;
    }
    m0 *= 0.25f; m1 *= 0.25f; m2 *= 0.25f; m3 *= 0.25f;
    // fold score partials over quads (16-ch partial of head hg for this wave's j)
    sh0 += __shfl_xor(sh0, 16); sh0 += __shfl_xor(sh0, 32);
    sh1 += __shfl_xor(sh1, 16); sh1 += __shfl_xor(sh1, 32);
    sh2 += __shfl_xor(sh2, 16); sh2 += __shfl_xor(sh2, 32);
    sh3 += __shfl_xor(sh3, 16); sh3 += __shfl_xor(sh3, 32);
    if (quad == 0)
      *(float4*)&sc_part[(long)e * 16 + w * 4] = make_float4(sh0, sh1, sh2, sh3);
    f_mid[(long)e * 16 + w * 4 + quad] = make_uint2(packbf(m0, m1), packbf(m2, m3));
  }
}

// Streaming fixup: per-edge InstanceNorm+ELU on f_mid -> f_next; sum 4 score
// partials -> sc_csr at CSR position. 8 lanes per edge.
__global__ __launch_bounds__(256) void fixup(
    const uint4* __restrict__ f_mid4, const float4* __restrict__ sc_part4,
    const int* __restrict__ csr_pos, uint4* __restrict__ f_next4,
    float4* __restrict__ sc_csr4)
{
  int tid = blockIdx.x * 256 + threadIdx.x;
  int e = tid >> 3, sub = tid & 7;
  uint4 mv = f_mid4[(long)e * 8 + sub];
  float4 p0 = up4(make_uint2(mv.x, mv.y));
  float4 p1 = up4(make_uint2(mv.z, mv.w));
  float s1 = p0.x + p0.y + p0.z + p0.w + p1.x + p1.y + p1.z + p1.w;
  float s2 = p0.x*p0.x + p0.y*p0.y + p0.z*p0.z + p0.w*p0.w
           + p1.x*p1.x + p1.y*p1.y + p1.z*p1.z + p1.w*p1.w;
  s1 += __shfl_xor(s1, 1); s2 += __shfl_xor(s2, 1);
  s1 += __shfl_xor(s1, 2); s2 += __shfl_xor(s2, 2);
  s1 += __shfl_xor(s1, 4); s2 += __shfl_xor(s2, 4);
  float mean = s1 * 0.015625f;
  float var  = s2 * 0.015625f - mean * mean;
  float rs = rsqrtf(var + 1e-5f);
  float o0 = (p0.x - mean) * rs; o0 = o0 > 0.f ? o0 : expm1f(o0);
  float o1 = (p0.y - mean) * rs; o1 = o1 > 0.f ? o1 : expm1f(o1);
  float o2 = (p0.z - mean) * rs; o2 = o2 > 0.f ? o2 : expm1f(o2);
  float o3 = (p0.w - mean) * rs; o3 = o3 > 0.f ? o3 : expm1f(o3);
  float o4 = (p1.x - mean) * rs; o4 = o4 > 0.f ? o4 : expm1f(o4);
  float o5 = (p1.y - mean) * rs; o5 = o5 > 0.f ? o5 : expm1f(o5);
  float o6 = (p1.z - mean) * rs; o6 = o6 > 0.f ? o6 : expm1f(o6);
  float o7 = (p1.w - mean) * rs; o7 = o7 > 0.f ? o7 : expm1f(o7);
  f_next4[(long)e * 8 + sub] =
      make_uint4(packbf(o0, o1), packbf(o2, o3), packbf(o4, o5), packbf(o6, o7));
  if (sub < 4) {
    float4 sp = sc_part4[(long)e * 4 + sub];
    sp.x += __shfl_xor(sp.x, 1); sp.y += __shfl_xor(sp.y, 1);
    sp.z += __shfl_xor(sp.z, 1); sp.w += __shfl_xor(sp.w, 1);
    sp.x += __shfl_xor(sp.x, 2); sp.y += __shfl_xor(sp.y, 2);
    sp.z += __shfl_xor(sp.z, 2); sp.w += __shfl_xor(sp.w, 2);
    if (sub == 0) sc_csr4[csr_pos[e]] = sp;
  }
}

// One wave per node: softmax weights over contiguous CSR scores + weighted sum of
// RAW h rows (128B, L2-resident) -> g[n][256] = per-head weighted mean (bf16).
__global__ __launch_bounds__(256) void agg_kernel(
    const uint* __restrict__ h_u, const float4* __restrict__ sc_csr4,
    const int* __restrict__ esrc, const int* __restrict__ off,
    uint* __restrict__ g_u)
{
  int n = (blockIdx.x * 256 + threadIdx.x) >> 6;
  int lane = threadIdx.x & 63;
  int half = lane >> 5, seg = lane & 31;
  int o0 = off[n], o1 = off[n + 1];
  if (o0 == o1) {
    g_u[(long)n * 128 + (half * 2) * 32 + seg] = 0u;
    g_u[(long)n * 128 + (half * 2 + 1) * 32 + seg] = 0u;
    return;
  }
  float mx0 = -3.0e38f, mx1 = -3.0e38f, mx2 = -3.0e38f, mx3 = -3.0e38f;
  for (int i = o0 + half; i < o1; i += 2) {
    float4 s = sc_csr4[i];
    mx0 = fmaxf(mx0, s.x); mx1 = fmaxf(mx1, s.y);
    mx2 = fmaxf(mx2, s.z); mx3 = fmaxf(mx3, s.w);
  }
  mx0 = fmaxf(mx0, __shfl_xor(mx0, 32)); mx1 = fmaxf(mx1, __shfl_xor(mx1, 32));
  mx2 = fmaxf(mx2, __shfl_xor(mx2, 32)); mx3 = fmaxf(mx3, __shfl_xor(mx3, 32));
  float d0 = 0.f, d1 = 0.f, d2 = 0.f, d3 = 0.f;
  float a00=0.f,a01=0.f,a10=0.f,a11=0.f,a20=0.f,a21=0.f,a30=0.f,a31=0.f;
  for (int i = o0 + half; i < o1; i += 2) {
    float4 s = sc_csr4[i];
    float w0 = __expf(s.x - mx0), w1 = __expf(s.y - mx1);
    float w2 = __expf(s.z - mx2), w3 = __expf(s.w - mx3);
    d0 += w0; d1 += w1; d2 += w2; d3 += w3;
    int sr = esrc[i];
    uint hv = h_u[(long)sr * 32 + seg];
    float hlo = __uint_as_float(hv << 16);
    float hhi = __uint_as_float(hv & 0xffff0000u);
    a00 = fmaf(w0, hlo, a00); a01 = fmaf(w0, hhi, a01);
    a10 = fmaf(w1, hlo, a10); a11 = fmaf(w1, hhi, a11);
    a20 = fmaf(w2, hlo, a20); a21 = fmaf(w2, hhi, a21);
    a30 = fmaf(w3, hlo, a30); a31 = fmaf(w3, hhi, a31);
  }
  d0 += __shfl_xor(d0, 32); d1 += __shfl_xor(d1, 32);
  d2 += __shfl_xor(d2, 32); d3 += __shfl_xor(d3, 32);
  a00 += __shfl_xor(a00, 32); a01 += __shfl_xor(a01, 32);
  a10 += __shfl_xor(a10, 32); a11 += __shfl_xor(a11, 32);
  a20 += __shfl_xor(a20, 32); a21 += __shfl_xor(a21, 32);
  a30 += __shfl_xor(a30, 32); a31 += __shfl_xor(a31, 32);
  float i0 = 1.f / d0, i1 = 1.f / d1, i2 = 1.f / d2, i3 = 1.f / d3;
  uint u0 = packbf(a00 * i0, a01 * i0);
  uint u1 = packbf(a10 * i1, a11 * i1);
  uint u2 = packbf(a20 * i2, a21 * i2);
  uint u3 = packbf(a30 * i3, a31 * i3);
  if (half == 0) {
    g_u[(long)n * 128 + seg] = u0;
    g_u[(long)n * 128 + 32 + seg] = u1;
  } else {
    g_u[(long)n * 128 + 64 + seg] = u2;
    g_u[(long)n * 128 + 96 + seg] = u3;
  }
}

// combine: h_next[n][c] = elu(inorm_c( g[n] @ WcT^T + bmean )) ; deg-0 -> 0.
// block = 32 nodes (2 chunks of 16), 4 waves split the 64 output channels.
__global__ __launch_bounds__(256) void combine(
    const uint4* __restrict__ g4, const uint4* __restrict__ WcT4,
    const float* __restrict__ bmean_l, const int* __restrict__ off,
    uint2* __restrict__ h_next)
{
  __shared__ float red[2][4][16][2];
  int t = threadIdx.x, lane = t & 63, w = t >> 6;
  int col = lane & 15, quad = lane >> 4;
  int c = w * 16 + col;
  bf16x8 A[8];
  #pragma unroll
  for (int kt = 0; kt < 8; kt++)
    A[kt] = *(const bf16x8*)&WcT4[c * 32 + kt * 4 + quad];
  int c2 = w * 16 + quad * 4;
  float4 bm = ld4(bmean_l + c2);
  for (int ch = 0; ch < 2; ch++) {
    int n = blockIdx.x * 32 + ch * 16 + col;
    int deg = off[n + 1] - off[n];
    f32x4 acc = (f32x4){0.f, 0.f, 0.f, 0.f};
    #pragma unroll
    for (int kt = 0; kt < 8; kt++) {
      bf16x8 B = *(const bf16x8*)&g4[(long)n * 32 + kt * 4 + quad];
      acc = __builtin_amdgcn_mfma_f32_16x16x32_bf16(A[kt], B, acc, 0, 0, 0);
    }
    float x0, x1, x2, x3;
    if (deg > 0) { x0 = acc[0] + bm.x; x1 = acc[1] + bm.y; x2 = acc[2] + bm.z; x3 = acc[3] + bm.w; }
    else { x0 = x1 = x2 = x3 = 0.f; }
    float s1 = x0 + x1 + x2 + x3;
    float s2 = x0*x0 + x1*x1 + x2*x2 + x3*x3;
    s1 += __shfl_xor(s1, 16); s2 += __shfl_xor(s2, 16);
    s1 += __shfl_xor(s1, 32); s2 += __shfl_xor(s2, 32);
    if (quad == 0) { red[ch][w][col][0] = s1; red[ch][w][col][1] = s2; }
    __syncthreads();
    float s1T = red[ch][0][col][0] + red[ch][1][col][0] + red[ch][2][col][0] + red[ch][3][col][0];
    float s2T = red[ch][0][col][1] + red[ch][1][col][1] + red[ch][2][col][1] + red[ch][3][col][1];
    float mean = s1T * 0.015625f;
    float var  = s2T * 0.015625f - mean * mean;
    float rs = rsqrtf(var + 1e-5f);
    float o0 = (x0 - mean) * rs; o0 = o0 > 0.f ? o0 : expm1f(o0);
    float o1 = (x1 - mean) * rs; o1 = o1 > 0.f ? o1 : expm1f(o1);
    float o2 = (x2 - mean) * rs; o2 = o2 > 0.f ? o2 : expm1f(o2);
    float o3 = (x3 - mean) * rs; o3 = o3 > 0.f ? o3 : expm1f(o3);
    h_next[(long)n * 16 + w * 4 + quad] = make_uint2(packbf(o0, o1), packbf(o2, o3));
  }
}

// out[m][j] = sum_k bf16(h)[m][k] * Wf[k][j] + bf[j]
__global__ void final_gemm(const uint2* __restrict__ h, const float* __restrict__ Wf,
                           const float* __restrict__ bf_, float* __restrict__ out) {
  int idx = blockIdx.x * 256 + threadIdx.x;
  if (idx >= NN * 16) return;
  int m = idx >> 4, j4 = (idx & 15) << 2;
  const uint2* row = h + (long)m * 16;
  float ax = 0.f, ay = 0.f, az = 0.f, aw = 0.f;
  for (int kk = 0; kk < 16; kk++) {
    float4 a = up4(row[kk]);
    float4 b0 = ld4(Wf + (kk * 4 + 0) * 64 + j4);
    float4 b1 = ld4(Wf + (kk * 4 + 1) * 64 + j4);
    float4 b2 = ld4(Wf + (kk * 4 + 2) * 64 + j4);
    float4 b3 = ld4(Wf + (kk * 4 + 3) * 64 + j4);
    ax = fmaf(a.x, b0.x, ax); ay = fmaf(a.x, b0.y, ay); az = fmaf(a.x, b0.z, az); aw = fmaf(a.x, b0.w, aw);
    ax = fmaf(a.y, b1.x, ax); ay = fmaf(a.y, b1.y, ay); az = fmaf(a.y, b1.z, az); aw = fmaf(a.y, b1.w, aw);
    ax = fmaf(a.z, b2.x, ax); ay = fmaf(a.z, b2.y, ay); az = fmaf(a.z, b2.z, az); aw = fmaf(a.z, b2.w, aw);
    ax = fmaf(a.w, b3.x, ax); ay = fmaf(a.w, b3.y, ay); az = fmaf(a.w, b3.z, az); aw = fmaf(a.w, b3.w, aw);
  }
  float4 bb = ld4(bf_ + j4);
  *(float4*)(out + (long)m * 64 + j4) = make_float4(ax + bb.x, ay + bb.y, az + bb.z, aw + bb.w);
}

extern "C" void kernel_launch(void* const* d_in, const int* in_sizes, int n_in,
                              void* d_out, int out_size, void* d_ws, size_t ws_size,
                              hipStream_t stream) {
  const float* x      = (const float*)d_in[0];
  const float* efeat  = (const float*)d_in[1];
  const int*   src    = (const int*)d_in[2];
  const int*   dst    = (const int*)d_in[3];
  const float* Wn0    = (const float*)d_in[4];
  const float* bn0    = (const float*)d_in[5];
  const float* We0    = (const float*)d_in[6];
  const float* be0    = (const float*)d_in[7];
  const float* Wnode  = (const float*)d_in[8];
  const float* bnode  = (const float*)d_in[9];
  const float* Wni    = (const float*)d_in[10];
  const float* Wnj    = (const float*)d_in[11];
  const float* Wfij   = (const float*)d_in[12];
  const float* attn   = (const float*)d_in[13];
  const float* bias_e = (const float*)d_in[14];
  const float* Wf     = (const float*)d_in[15];
  const float* bf     = (const float*)d_in[16];
  float* out = (float*)d_out;

  char* w = (char*)d_ws;
  auto alloc = [&](size_t nbytes) { char* p = w; w += (nbytes + 255) & ~(size_t)255; return p; };
  uint2* h_a   = (uint2*)alloc((size_t)NN * 128);    // bf16 [NN][64]
  uint2* h_b   = (uint2*)alloc((size_t)NN * 128);
  uint2* f_a   = (uint2*)alloc((size_t)NE * 128);    // bf16 [NE][64]
  uint2* f_b   = (uint2*)alloc((size_t)NE * 128);
  uint2* f_mid = (uint2*)alloc((size_t)NE * 128);    // unnormalized head-mean partials
  float* scp   = (float*)alloc((size_t)NE * 64);     // per-wave score partials [E][16]
  float* scc   = (float*)alloc((size_t)NE * 16);     // summed scores, CSR order [E][4]
  uint*  g     = (uint*)alloc((size_t)NN * 512);     // bf16 [NN][256]
  uint*  Wcat  = (uint*)alloc((size_t)2 * 24576 * 4);
  uint*  WcT   = (uint*)alloc((size_t)2 * 8192 * 4);
  float* bmean = (float*)alloc((size_t)2 * 64 * 4);
  int* deg     = (int*)alloc((size_t)NN * 2 * 4);
  int* cursor  = deg + NN;
  int* off     = (int*)alloc((size_t)(NN + 1) * 4);
  int* esrc    = (int*)alloc((size_t)NE * 4);
  int* csr_pos = (int*)alloc((size_t)NE * 4);
  int* bsum    = (int*)alloc((size_t)128 * 4);

  gemm4_bf16<<<(NN * 16 + 255) / 256, 256, 0, stream>>>(x, Wn0, bn0, h_a, NN, 65, 64);
  gemm4_bf16<<<(NE * 16 + 255) / 256, 256, 0, stream>>>(efeat, We0, be0, f_a, NE, 15, 64);
  prep_w<<<4, 256, 0, stream>>>(Wni, Wnj, Wfij, Wnode, bnode, Wcat, WcT, bmean);

  zero_i32<<<(2 * NN + 255) / 256, 256, 0, stream>>>(deg, 2 * NN);
  count_deg<<<(NE + 255) / 256, 256, 0, stream>>>(dst, deg);
  scan1<<<SCAN_BLOCKS, 256, 0, stream>>>(deg, off, bsum);
  scan2<<<1, 128, 0, stream>>>(bsum, off);
  scan3<<<SCAN_BLOCKS, 256, 0, stream>>>(off, bsum);
  fill_csr<<<(NE + 255) / 256, 256, 0, stream>>>(dst, src, off, cursor, esrc, csr_pos);

  uint2* hc = h_a; uint2* hn = h_b;
  uint2* fc = f_a; uint2* fn = f_b;
  for (int l = 0; l < 2; l++) {
    const uint* Wcat_l = Wcat + (size_t)l * 24576;
    const uint4* WcT_l = (const uint4*)(WcT + (size_t)l * 8192);
    const float* bm_l  = bmean + (size_t)l * 64;
    const float* be_l  = bias_e + (size_t)l * 256;
    const float* at_l  = attn + (size_t)l * 256;
    edge_mfma<<<NE / 64, 256, 0, stream>>>((const uint4*)fc, (const uint4*)hc,
                                           Wcat_l, be_l, at_l, src, dst, scp, f_mid);
    fixup<<<NE / 32, 256, 0, stream>>>((const uint4*)f_mid, (const float4*)scp,
                                       csr_pos, (uint4*)fn, (float4*)scc);
    agg_kernel<<<NN / 4, 256, 0, stream>>>((const uint*)hc, (const float4*)scc,
                                           esrc, off, g);
    combine<<<NN / 32, 256, 0, stream>>>((const uint4*)g, WcT_l, bm_l, off, hn);
    uint2* tmp = hc; hc = hn; hn = tmp;
    tmp = fc; fc = fn; fn = tmp;
  }
  final_gemm<<<(NN * 16 + 255) / 256, 256, 0, stream>>>(hc, Wf, bf, out);
}